// Round 15
// baseline (141.241 us; speedup 1.0000x reference)
//
#include <hip/hip_runtime.h>

// Fused MHA: x->QKV proj (bf16 MFMA) -> causal flash attn -> O proj.
// B=2, T=2048, D=1024, H=16, HD=64.
// Round 15: attn rewritten on 32x32x16 MFMA with in-register P:
// swapped QK (S^T = K*Q^T) -> lane owns q-col; P re-pack for PV via
// cvtpk + v_permlane32_swap + select (NO LDS round-trip, no lgkm chain).
// 4 waves x 32q, KVBLK=64, mod-3 buffers (r12 sync). qkv/out/cvt = r14.

#define DEV __device__ __forceinline__

typedef __attribute__((ext_vector_type(8))) __bf16 bf16x8;
typedef __attribute__((ext_vector_type(4))) float f32x4;
typedef __attribute__((ext_vector_type(16))) float f32x16;

DEV unsigned short f2bf(float f) {
  union { float f; unsigned u; } c;
  c.f = f;
  unsigned u = c.u + 0x7FFFu + ((c.u >> 16) & 1u);  // RTNE
  return (unsigned short)(u >> 16);
}

DEV unsigned cvtpk(float lo, float hi) {
  unsigned r;
  asm("v_cvt_pk_bf16_f32 %0, %1, %2" : "=v"(r) : "v"(lo), "v"(hi));
  return r;
}

DEV void gload16(const unsigned short* g, unsigned short* l) {
  __builtin_amdgcn_global_load_lds(
      (const __attribute__((address_space(1))) unsigned int*)g,
      (__attribute__((address_space(3))) unsigned int*)l, 16, 0, 0);
}

DEV f32x4 mfma16(bf16x8 a, bf16x8 b, f32x4 c) {
  return __builtin_amdgcn_mfma_f32_16x16x32_bf16(a, b, c, 0, 0, 0);
}

DEV f32x16 mfma32(bf16x8 a, bf16x8 b, f32x16 c) {
  return __builtin_amdgcn_mfma_f32_32x32x16_bf16(a, b, c, 0, 0, 0);
}

#define WAITVM(n) asm volatile("s_waitcnt vmcnt(" #n ")" ::: "memory")
#define WAITLGKM() asm volatile("s_waitcnt lgkmcnt(0)" ::: "memory")
#define BAR() __builtin_amdgcn_s_barrier()
#define SCHEDB() __builtin_amdgcn_sched_barrier(0)
#define PRIO(n) __builtin_amdgcn_s_setprio(n)

// ---------------- fp32 -> bf16 convert (all 5 tensors, one launch) -------
__global__ __launch_bounds__(256) void k_cvt_all(
    const float* __restrict__ x, const float* __restrict__ wq,
    const float* __restrict__ wk, const float* __restrict__ wv,
    const float* __restrict__ wo, unsigned short* __restrict__ dst) {
  int i = blockIdx.x * blockDim.x + threadIdx.x;  // float4 index
  const float* s;
  int off;
  if (i < 1048576) {
    s = x; off = i;
  } else {
    int j = i - 1048576;
    int w = j >> 18;
    off = j & 262143;
    s = (w == 0) ? wq : (w == 1) ? wk : (w == 2) ? wv : wo;
  }
  float4 v = reinterpret_cast<const float4*>(s)[off];
  uint2 o;
  o.x = (unsigned)f2bf(v.x) | ((unsigned)f2bf(v.y) << 16);
  o.y = (unsigned)f2bf(v.z) | ((unsigned)f2bf(v.w) << 16);
  reinterpret_cast<uint2*>(dst)[i] = o;
}

// ---------------- FUSED QKV projection (128x64 tiles, 3 modes) ----------
__global__ __launch_bounds__(256) void k_gemm_qkv(
    const unsigned short* __restrict__ X, const unsigned short* __restrict__ Wq,
    const unsigned short* __restrict__ Wk, const unsigned short* __restrict__ Wv,
    const float* __restrict__ bq, const float* __restrict__ bk,
    const float* __restrict__ bv, unsigned short* __restrict__ Qo,
    unsigned short* __restrict__ Ko, unsigned short* __restrict__ Vo) {
  __shared__ unsigned short ls[20480];  // X 2x4096 | Wq 2x2048 | Wk | Wv
  unsigned short* la0 = ls;
  unsigned short* lbq = ls + 8192;
  unsigned short* lbk = ls + 12288;
  unsigned short* lbv = ls + 16384;

  const int id = blockIdx.x;
  const int xcd = id & 7, s4 = id >> 3;
  const int bx = ((s4 >> 3) & 7) * 2 + (xcd & 1);  // 0..15
  const int by = (s4 & 7) * 4 + (xcd >> 1);        // 0..31
  const int m0 = by * 128, n0 = bx * 64;

  const int tid = threadIdx.x;
  const int lane = tid & 63, wave = tid >> 6;
  const int l15 = lane & 15, g = lane >> 4;
  const int wm = (wave >> 1) * 64, wn = (wave & 1) * 32;
  const int g16 = g << 4;
  const int sx = (lane & 3) << 4;

  f32x4 a0[4][2] = {}, a1[4][2] = {}, a2[4][2] = {};

#define STG_QKV(buf, k0)                                                     \
  {                                                                          \
    _Pragma("unroll") for (int i = 0; i < 2; ++i) {                          \
      const int c = i * 256 + tid;                                           \
      const int row = c >> 2;                                                \
      const int scb = ((c & 3) << 4) ^ ((row & 3) << 4);                     \
      gload16(X + (m0 + row) * 1024 + (k0) + (scb >> 1),                     \
              (unsigned short*)((char*)(la0 + (buf)*4096) + c * 16));        \
    }                                                                        \
    {                                                                        \
      const int row = tid >> 2;                                              \
      const int scb = ((tid & 3) << 4) ^ ((row & 3) << 4);                   \
      const int go = (n0 + row) * 1024 + (k0) + (scb >> 1);                  \
      gload16(Wq + go,                                                       \
              (unsigned short*)((char*)(lbq + (buf)*2048) + tid * 16));      \
      gload16(Wk + go,                                                       \
              (unsigned short*)((char*)(lbk + (buf)*2048) + tid * 16));      \
      gload16(Wv + go,                                                       \
              (unsigned short*)((char*)(lbv + (buf)*2048) + tid * 16));      \
    }                                                                        \
  }

  STG_QKV(0, 0);
  __syncthreads();

  for (int kt = 0; kt < 32; ++kt) {
    const int cur = kt & 1;
    if (kt + 1 < 32) STG_QKV(cur ^ 1, (kt + 1) * 32);
    unsigned short* la = la0 + cur * 4096;
    bf16x8 af[4];
#pragma unroll
    for (int m = 0; m < 4; ++m)
      af[m] = *reinterpret_cast<const bf16x8*>(
          (char*)la + (wm + m * 16 + l15) * 64 + (g16 ^ sx));
    {
      unsigned short* lb = lbq + cur * 2048;
      bf16x8 bfr[2];
#pragma unroll
      for (int n = 0; n < 2; ++n)
        bfr[n] = *reinterpret_cast<const bf16x8*>(
            (char*)lb + (wn + n * 16 + l15) * 64 + (g16 ^ sx));
#pragma unroll
      for (int m = 0; m < 4; ++m)
#pragma unroll
        for (int n = 0; n < 2; ++n) a0[m][n] = mfma16(af[m], bfr[n], a0[m][n]);
    }
    {
      unsigned short* lb = lbk + cur * 2048;
      bf16x8 bfr[2];
#pragma unroll
      for (int n = 0; n < 2; ++n)
        bfr[n] = *reinterpret_cast<const bf16x8*>(
            (char*)lb + (wn + n * 16 + l15) * 64 + (g16 ^ sx));
#pragma unroll
      for (int m = 0; m < 4; ++m)
#pragma unroll
        for (int n = 0; n < 2; ++n) a1[m][n] = mfma16(af[m], bfr[n], a1[m][n]);
    }
    {
      unsigned short* lb = lbv + cur * 2048;
      bf16x8 bfr[2];
#pragma unroll
      for (int n = 0; n < 2; ++n)
        bfr[n] = *reinterpret_cast<const bf16x8*>(
            (char*)lb + (wn + n * 16 + l15) * 64 + (g16 ^ sx));
#pragma unroll
      for (int m = 0; m < 4; ++m)
#pragma unroll
        for (int n = 0; n < 2; ++n) a2[m][n] = mfma16(af[m], bfr[n], a2[m][n]);
    }
    __syncthreads();
  }
#undef STG_QKV

  unsigned short* lw = ls + wave * 2048;
  const int h = (n0 + wn) >> 6;
  const int hd0 = (n0 + wn) & 63;
  const int rb = m0 + wm;
  const int b = rb >> 11;
  const int tb0 = rb & 2047;

#pragma unroll
  for (int mode = 0; mode < 2; ++mode) {
    const float* bias = mode ? bk : bq;
    const float sc = mode ? 1.0f : 0.180336880f;  // 0.125 * log2(e)
    unsigned short* dst = mode ? Ko : Qo;
    WAITLGKM();
#pragma unroll
    for (int m = 0; m < 4; ++m)
#pragma unroll
      for (int n = 0; n < 2; ++n) {
        const float bb = bias[n0 + wn + n * 16 + l15];
        const f32x4 av = mode ? a1[m][n] : a0[m][n];
#pragma unroll
        for (int r = 0; r < 4; ++r)
          lw[(m * 16 + (g << 2) + r) * 32 + n * 16 + l15] =
              f2bf((av[r] + bb) * sc);
      }
    WAITLGKM();
    SCHEDB();
#pragma unroll
    for (int it = 0; it < 4; ++it) {
      const int rr = (lane >> 2) + it * 16;
      const int ck = (lane & 3) * 8;
      uint4 v = *reinterpret_cast<const uint4*>(&lw[rr * 32 + ck]);
      *reinterpret_cast<uint4*>(
          &dst[(((b << 4) + h) * 2048 + tb0 + rr) * 64 + hd0 + ck]) = v;
    }
  }

  WAITLGKM();
#pragma unroll
  for (int m = 0; m < 4; ++m)
#pragma unroll
    for (int n = 0; n < 2; ++n) {
      const float bb = bv[n0 + wn + n * 16 + l15];
      uint2 w;
      w.x = cvtpk(a2[m][n][0] + bb, a2[m][n][1] + bb);
      w.y = cvtpk(a2[m][n][2] + bb, a2[m][n][3] + bb);
      *reinterpret_cast<uint2*>(&lw[(n * 16 + l15) * 64 + m * 16 + (g << 2)]) =
          w;
    }
  WAITLGKM();
  SCHEDB();
#pragma unroll
  for (int it = 0; it < 4; ++it) {
    const int hdr = (lane >> 3) + it * 8;
    const int ck = (lane & 7) * 8;
    uint4 v = *reinterpret_cast<const uint4*>(&lw[hdr * 64 + ck]);
    *reinterpret_cast<uint4*>(
        &Vo[(((b << 4) + h) * 64 + hd0 + hdr) * 2048 + tb0 + ck]) = v;
  }
}

// ---------------- output projection (128x64 tiles, fp32 out + bias) ------
__global__ __launch_bounds__(256) void k_gemm_out(
    const unsigned short* __restrict__ Ctx, const unsigned short* __restrict__ Wo,
    const float* __restrict__ bo, float* __restrict__ Out) {
  __shared__ unsigned short ls[16384];
  unsigned short* la0 = ls;
  unsigned short* lb0 = ls + 8192;
  const int id = blockIdx.x;
  const int xcd = id & 7, s4 = id >> 3;
  const int bx = ((s4 >> 3) & 7) * 2 + (xcd & 1);
  const int by = (s4 & 7) * 4 + (xcd >> 1);
  const int tid = threadIdx.x;
  const int lane = tid & 63, wave = tid >> 6;
  const int l15 = lane & 15, g = lane >> 4;
  const int m0 = by * 128, n0 = bx * 64;
  const int wm = (wave >> 1) * 64, wn = (wave & 1) * 32;
  const int g16 = (g << 4);
  const int sx = (lane & 3) << 4;
  f32x4 acc[4][2] = {};

#define STG_OUT(buf, k0)                                                     \
  {                                                                          \
    _Pragma("unroll") for (int i = 0; i < 2; ++i) {                          \
      const int c = i * 256 + tid;                                           \
      const int row = c >> 2;                                                \
      const int scb = (((c & 3) << 4)) ^ ((row & 3) << 4);                   \
      gload16(Ctx + (m0 + row) * 1024 + (k0) + (scb >> 1),                   \
              (unsigned short*)((char*)(la0 + (buf)*4096) + c * 16));        \
    }                                                                        \
    {                                                                        \
      const int row = tid >> 2;                                              \
      const int scb = (((tid & 3) << 4)) ^ ((row & 3) << 4);                 \
      gload16(Wo + (n0 + row) * 1024 + (k0) + (scb >> 1),                    \
              (unsigned short*)((char*)(lb0 + (buf)*2048) + tid * 16));      \
    }                                                                        \
  }

  STG_OUT(0, 0);
  __syncthreads();

  for (int kt = 0; kt < 32; ++kt) {
    const int cur = kt & 1;
    unsigned short* la = la0 + cur * 4096;
    unsigned short* lb = lb0 + cur * 2048;
    if (kt + 1 < 32) STG_OUT(cur ^ 1, (kt + 1) * 32);
    bf16x8 af[4], bfr[2];
#pragma unroll
    for (int m = 0; m < 4; ++m)
      af[m] = *reinterpret_cast<const bf16x8*>(
          (char*)la + (wm + m * 16 + l15) * 64 + (g16 ^ sx));
#pragma unroll
    for (int n = 0; n < 2; ++n)
      bfr[n] = *reinterpret_cast<const bf16x8*>(
          (char*)lb + (wn + n * 16 + l15) * 64 + (g16 ^ sx));
#pragma unroll
    for (int m = 0; m < 4; ++m)
#pragma unroll
      for (int n = 0; n < 2; ++n)
        acc[m][n] = mfma16(af[m], bfr[n], acc[m][n]);
    __syncthreads();
  }
#undef STG_OUT

  float* lwf = (float*)(ls + wave * 4096);
#pragma unroll
  for (int m = 0; m < 4; ++m)
#pragma unroll
    for (int n = 0; n < 2; ++n) {
      const float bb = bo[n0 + wn + n * 16 + l15];
#pragma unroll
      for (int r = 0; r < 4; ++r)
        lwf[(m * 16 + (g << 2) + r) * 32 + n * 16 + l15] = acc[m][n][r] + bb;
    }
  WAITLGKM();
  SCHEDB();
#pragma unroll
  for (int it = 0; it < 8; ++it) {
    const int rr = (lane >> 3) + it * 8;
    const int ck = (lane & 7) * 4;
    float4 v = *reinterpret_cast<const float4*>(&lwf[rr * 32 + ck]);
    *reinterpret_cast<float4*>(&Out[(m0 + wm + rr) * 1024 + n0 + wn + ck]) = v;
  }
}

// ---------------- causal flash attention (32x32 MFMA, in-register P) -----
// grid 512 1-D, xcd = bh%8. 4 waves x 32 q-rows: waves 0-1 = tile qtB,
// waves 2-3 = tile qtA. KVBLK=64, mod-3 LDS buffers, r12 sync
// (WAITVM(4) -> BAR -> stage(t+2) -> compute(t)).
// S^T = mfma32(K, Q^T): lane owns q-col = lane&31, kv rows
// (r&3)+8*(r>>2)+4*(lane>>5). P re-pack to PV B-frag via
// cvtpk + v_permlane32_swap + select. O^T accumulated in 2x f32x16.

DEV void attn_stage64(const unsigned short* __restrict__ Kb,
                      const unsigned short* __restrict__ Vb,
                      unsigned short* lk, unsigned short* lv, int kv0,
                      int tid) {
#pragma unroll
  for (int i = 0; i < 2; ++i) {
    const int c = i * 256 + tid;  // 0..511 chunks of 16B
    const int row = c >> 3;
    const int scb = ((c & 7) << 4) ^ ((row & 7) << 4);
    gload16(Kb + (kv0 + row) * 64 + (scb >> 1), lk + c * 8);
    gload16(Vb + row * 2048 + kv0 + (scb >> 1), lv + c * 8);
  }
}

DEV void attn_step32(const unsigned short* lk, const unsigned short* lv,
                     const bf16x8 (&qf)[4], f32x16& O0, f32x16& O1,
                     float& ls, int lane, int sub, int kvg0, int qg,
                     bool diag) {
  const int l31 = lane & 31;
  const int hi = lane >> 5;
  const int h16 = hi << 4;
  const int sw = (l31 & 7) << 4;
  f32x16 st = {};
  PRIO(1);
#pragma unroll
  for (int m = 0; m < 4; ++m) {
    bf16x8 kf = *reinterpret_cast<const bf16x8*>(
        (const char*)lk + (sub * 32 + l31) * 128 + ((m * 32 + h16) ^ sw));
    st = mfma32(kf, qf[m], st);
  }
  PRIO(0);
  if (diag) {
#pragma unroll
    for (int r = 0; r < 16; ++r) {
      const int kvl = (r & 3) + 8 * (r >> 2) + 4 * hi;
      if (kvg0 + sub * 32 + kvl > qg) st[r] = -1e30f;
    }
  }
  float rs = 0.f;
#pragma unroll
  for (int r = 0; r < 16; ++r) {
    float p = exp2f(st[r]);
    st[r] = p;
    rs += p;
  }
  ls += rs;
#pragma unroll
  for (int m2 = 0; m2 < 2; ++m2) {
    unsigned a0 = cvtpk(st[m2 * 8 + 0], st[m2 * 8 + 1]);
    unsigned a1 = cvtpk(st[m2 * 8 + 2], st[m2 * 8 + 3]);
    unsigned a2 = cvtpk(st[m2 * 8 + 4], st[m2 * 8 + 5]);
    unsigned a3 = cvtpk(st[m2 * 8 + 6], st[m2 * 8 + 7]);
    unsigned b0 = a0, b1 = a1, b2 = a2, b3 = a3;
    asm("v_permlane32_swap_b32 %0, %1" : "+v"(a0), "+v"(b0));
    asm("v_permlane32_swap_b32 %0, %1" : "+v"(a1), "+v"(b1));
    asm("v_permlane32_swap_b32 %0, %1" : "+v"(a2), "+v"(b2));
    asm("v_permlane32_swap_b32 %0, %1" : "+v"(a3), "+v"(b3));
    // a* = half0's packed words (bcast both halves), b* = half1's.
    union { unsigned u[4]; bf16x8 v; } pb;
    pb.u[0] = hi ? a2 : a0;
    pb.u[1] = hi ? a3 : a1;
    pb.u[2] = hi ? b2 : b0;
    pb.u[3] = hi ? b3 : b1;
    PRIO(1);
    {
      const int vb = (sub * 64 + m2 * 32 + h16) ^ sw;
      bf16x8 vf0 = *reinterpret_cast<const bf16x8*>(
          (const char*)lv + l31 * 128 + vb);
      O0 = mfma32(vf0, pb.v, O0);
      bf16x8 vf1 = *reinterpret_cast<const bf16x8*>(
          (const char*)lv + (32 + l31) * 128 + vb);
      O1 = mfma32(vf1, pb.v, O1);
    }
    PRIO(0);
  }
}

__global__ __launch_bounds__(256) void k_attn(
    const unsigned short* __restrict__ Q, const unsigned short* __restrict__ K,
    const unsigned short* __restrict__ Vt, unsigned short* __restrict__ Ctx) {
  __shared__ unsigned short lk[3][4096];  // K [64 kv][64 d], mod-3
  __shared__ unsigned short lv[3][4096];  // V^T [64 d][64 kv], mod-3

  const int tid = threadIdx.x, lane = tid & 63, wave = tid >> 6;
  const int id = blockIdx.x;
  const int xcd = id & 7, r4 = id >> 3;
  const int ip = r4 & 15;
  const int bh = ((r4 >> 4) << 3) + xcd;

  const int qtA = ip;
  const int qtB = 31 - ip;
  const int nt = qtB + 1;

  const int qt = (wave < 2) ? qtB : qtA;
  const int qoff = (wave & 1) << 5;
  const int l31 = lane & 31, hi = lane >> 5;
  const int qg = qt * 64 + qoff + l31;

  const unsigned short* Kb = K + bh * 2048 * 64;
  const unsigned short* Vb = Vt + bh * 64 * 2048;

  bf16x8 qf[4];
  {
    const unsigned short* qr = Q + (bh * 2048 + qg) * 64 + (hi << 3);
#pragma unroll
    for (int m = 0; m < 4; ++m)
      qf[m] = *reinterpret_cast<const bf16x8*>(qr + m * 16);
  }

  f32x16 O0 = {}, O1 = {};
  float ls = 0.f;

  attn_stage64(Kb, Vb, lk[0], lv[0], 0, tid);
  attn_stage64(Kb, Vb, lk[1], lv[1], 64, tid);

  for (int t = 0; t < nt; ++t) {
    WAITVM(4);  // stage(t) landed; stage(t+1) stays in flight
    BAR();      // compute(t-1) done on all waves; stage(t) visible
    {
      const int nx = (t + 2 < nt) ? t + 2 : nt - 1;  // clamp: redundant
      attn_stage64(Kb, Vb, lk[(t + 2) % 3], lv[(t + 2) % 3], nx * 64, tid);
    }
    SCHEDB();
    if (t <= qt) {
      const unsigned short* lkc = lk[t % 3];
      const unsigned short* lvc = lv[t % 3];
      const bool dg = (t == qt);
      attn_step32(lkc, lvc, qf, O0, O1, ls, lane, 0, t * 64, qg, dg);
      attn_step32(lkc, lvc, qf, O0, O1, ls, lane, 1, t * 64, qg, dg);
    }
  }

  WAITVM(0);  // drain DMA (LDS reallocation hazard + epilogue overlay)
  BAR();

  // epilogue: O^T regs -> per-wave LDS [32 q][72 shorts] -> coalesced store
  float lt = ls + __shfl_xor(ls, 32);
  const float inv = 1.f / lt;
  char* lw = (char*)lk + wave * 4608;

#pragma unroll
  for (int r2 = 0; r2 < 4; ++r2) {
    const int d0 = 8 * r2 + 4 * hi;
    uint2 w;
    w.x = cvtpk(O0[4 * r2] * inv, O0[4 * r2 + 1] * inv);
    w.y = cvtpk(O0[4 * r2 + 2] * inv, O0[4 * r2 + 3] * inv);
    *reinterpret_cast<uint2*>(lw + l31 * 144 + d0 * 2) = w;
  }
#pragma unroll
  for (int r2 = 0; r2 < 4; ++r2) {
    const int d0 = 32 + 8 * r2 + 4 * hi;
    uint2 w;
    w.x = cvtpk(O1[4 * r2] * inv, O1[4 * r2 + 1] * inv);
    w.y = cvtpk(O1[4 * r2 + 2] * inv, O1[4 * r2 + 3] * inv);
    *reinterpret_cast<uint2*>(lw + l31 * 144 + d0 * 2) = w;
  }
  WAITLGKM();
  SCHEDB();

  const int row = lane >> 1, half = lane & 1;
  const int qg2 = qt * 64 + qoff + row;
  const int b = bh >> 4, hh = bh & 15;
#pragma unroll
  for (int k = 0; k < 4; ++k) {
    uint4 v = *reinterpret_cast<const uint4*>(lw + row * 144 + half * 64 + k * 16);
    *reinterpret_cast<uint4*>(
        &Ctx[(b * 2048 + qg2) * 1024 + hh * 64 + half * 32 + k * 8]) = v;
  }
}

// ---------------- launch ----------------
extern "C" void kernel_launch(void* const* d_in, const int* in_sizes, int n_in,
                              void* d_out, int out_size, void* d_ws,
                              size_t ws_size, hipStream_t stream) {
  const float* x = (const float*)d_in[0];
  const float* Wq = (const float*)d_in[1];
  const float* bq = (const float*)d_in[2];
  const float* Wk = (const float*)d_in[3];
  const float* bk = (const float*)d_in[4];
  const float* Wv = (const float*)d_in[5];
  const float* bv = (const float*)d_in[6];
  const float* Wo = (const float*)d_in[7];
  const float* bo = (const float*)d_in[8];
  float* out = (float*)d_out;

  char* ws = (char*)d_ws;
  unsigned short* xb = (unsigned short*)(ws);                    // 8 MB
  unsigned short* wqb = (unsigned short*)(ws + (8u << 20));      // 2 MB
  unsigned short* wkb = (unsigned short*)(ws + (10u << 20));
  unsigned short* wvb = (unsigned short*)(ws + (12u << 20));
  unsigned short* wob = (unsigned short*)(ws + (14u << 20));
  unsigned short* Qb = (unsigned short*)(ws + (16u << 20));      // 8 MB
  unsigned short* Kb = (unsigned short*)(ws + (24u << 20));      // 8 MB
  unsigned short* Vtb = (unsigned short*)(ws + (32u << 20));     // 8 MB
  unsigned short* Ctx = (unsigned short*)(ws + (40u << 20));     // 8 MB

  k_cvt_all<<<8192, 256, 0, stream>>>(x, Wq, Wk, Wv, Wo, xb);

  k_gemm_qkv<<<512, 256, 0, stream>>>(xb, wqb, wkb, wvb, bq, bk, bv,
                                      Qb, Kb, Vtb);
  k_attn<<<512, 256, 0, stream>>>(Qb, Kb, Vtb, Ctx);
  k_gemm_out<<<512, 256, 0, stream>>>(Ctx, wob, bo, out);
}

// Round 16
// 127.634 us; speedup vs baseline: 1.1066x; 1.1066x over previous
//
#include <hip/hip_runtime.h>

// Fused MHA: x->QKV proj (bf16 MFMA) -> causal flash attn -> O proj.
// B=2, T=2048, D=1024, H=16, HD=64.
// Round 16: attn = r15's 32x32-MFMA in-register-P core (proven correct) +
// KV-SPLIT for TLP: 512-thread blocks, waves 0-3 sweep KV [0,hB), waves 4-7
// sweep [hB,nt) for the same q-rows; partials combined via LDS at the end.
// 2 tile streams, each double-buffered; 64KB LDS -> 2 blocks/CU, 16 waves/CU.
// qkv (fused) / out / cvt = r14 unchanged.

#define DEV __device__ __forceinline__

typedef __attribute__((ext_vector_type(8))) __bf16 bf16x8;
typedef __attribute__((ext_vector_type(4))) float f32x4;
typedef __attribute__((ext_vector_type(16))) float f32x16;

DEV unsigned short f2bf(float f) {
  union { float f; unsigned u; } c;
  c.f = f;
  unsigned u = c.u + 0x7FFFu + ((c.u >> 16) & 1u);  // RTNE
  return (unsigned short)(u >> 16);
}

DEV unsigned cvtpk(float lo, float hi) {
  unsigned r;
  asm("v_cvt_pk_bf16_f32 %0, %1, %2" : "=v"(r) : "v"(lo), "v"(hi));
  return r;
}

DEV void gload16(const unsigned short* g, unsigned short* l) {
  __builtin_amdgcn_global_load_lds(
      (const __attribute__((address_space(1))) unsigned int*)g,
      (__attribute__((address_space(3))) unsigned int*)l, 16, 0, 0);
}

DEV f32x4 mfma16(bf16x8 a, bf16x8 b, f32x4 c) {
  return __builtin_amdgcn_mfma_f32_16x16x32_bf16(a, b, c, 0, 0, 0);
}

DEV f32x16 mfma32(bf16x8 a, bf16x8 b, f32x16 c) {
  return __builtin_amdgcn_mfma_f32_32x32x16_bf16(a, b, c, 0, 0, 0);
}

#define WAITVM(n) asm volatile("s_waitcnt vmcnt(" #n ")" ::: "memory")
#define WAITLGKM() asm volatile("s_waitcnt lgkmcnt(0)" ::: "memory")
#define BAR() __builtin_amdgcn_s_barrier()
#define SCHEDB() __builtin_amdgcn_sched_barrier(0)
#define PRIO(n) __builtin_amdgcn_s_setprio(n)

// ---------------- fp32 -> bf16 convert (all 5 tensors, one launch) -------
__global__ __launch_bounds__(256) void k_cvt_all(
    const float* __restrict__ x, const float* __restrict__ wq,
    const float* __restrict__ wk, const float* __restrict__ wv,
    const float* __restrict__ wo, unsigned short* __restrict__ dst) {
  int i = blockIdx.x * blockDim.x + threadIdx.x;  // float4 index
  const float* s;
  int off;
  if (i < 1048576) {
    s = x; off = i;
  } else {
    int j = i - 1048576;
    int w = j >> 18;
    off = j & 262143;
    s = (w == 0) ? wq : (w == 1) ? wk : (w == 2) ? wv : wo;
  }
  float4 v = reinterpret_cast<const float4*>(s)[off];
  uint2 o;
  o.x = (unsigned)f2bf(v.x) | ((unsigned)f2bf(v.y) << 16);
  o.y = (unsigned)f2bf(v.z) | ((unsigned)f2bf(v.w) << 16);
  reinterpret_cast<uint2*>(dst)[i] = o;
}

// ---------------- FUSED QKV projection (128x64 tiles, 3 modes) ----------
__global__ __launch_bounds__(256) void k_gemm_qkv(
    const unsigned short* __restrict__ X, const unsigned short* __restrict__ Wq,
    const unsigned short* __restrict__ Wk, const unsigned short* __restrict__ Wv,
    const float* __restrict__ bq, const float* __restrict__ bk,
    const float* __restrict__ bv, unsigned short* __restrict__ Qo,
    unsigned short* __restrict__ Ko, unsigned short* __restrict__ Vo) {
  __shared__ unsigned short ls[20480];  // X 2x4096 | Wq 2x2048 | Wk | Wv
  unsigned short* la0 = ls;
  unsigned short* lbq = ls + 8192;
  unsigned short* lbk = ls + 12288;
  unsigned short* lbv = ls + 16384;

  const int id = blockIdx.x;
  const int xcd = id & 7, s4 = id >> 3;
  const int bx = ((s4 >> 3) & 7) * 2 + (xcd & 1);  // 0..15
  const int by = (s4 & 7) * 4 + (xcd >> 1);        // 0..31
  const int m0 = by * 128, n0 = bx * 64;

  const int tid = threadIdx.x;
  const int lane = tid & 63, wave = tid >> 6;
  const int l15 = lane & 15, g = lane >> 4;
  const int wm = (wave >> 1) * 64, wn = (wave & 1) * 32;
  const int g16 = g << 4;
  const int sx = (lane & 3) << 4;

  f32x4 a0[4][2] = {}, a1[4][2] = {}, a2[4][2] = {};

#define STG_QKV(buf, k0)                                                     \
  {                                                                          \
    _Pragma("unroll") for (int i = 0; i < 2; ++i) {                          \
      const int c = i * 256 + tid;                                           \
      const int row = c >> 2;                                                \
      const int scb = ((c & 3) << 4) ^ ((row & 3) << 4);                     \
      gload16(X + (m0 + row) * 1024 + (k0) + (scb >> 1),                     \
              (unsigned short*)((char*)(la0 + (buf)*4096) + c * 16));        \
    }                                                                        \
    {                                                                        \
      const int row = tid >> 2;                                              \
      const int scb = ((tid & 3) << 4) ^ ((row & 3) << 4);                   \
      const int go = (n0 + row) * 1024 + (k0) + (scb >> 1);                  \
      gload16(Wq + go,                                                       \
              (unsigned short*)((char*)(lbq + (buf)*2048) + tid * 16));      \
      gload16(Wk + go,                                                       \
              (unsigned short*)((char*)(lbk + (buf)*2048) + tid * 16));      \
      gload16(Wv + go,                                                       \
              (unsigned short*)((char*)(lbv + (buf)*2048) + tid * 16));      \
    }                                                                        \
  }

  STG_QKV(0, 0);
  __syncthreads();

  for (int kt = 0; kt < 32; ++kt) {
    const int cur = kt & 1;
    if (kt + 1 < 32) STG_QKV(cur ^ 1, (kt + 1) * 32);
    unsigned short* la = la0 + cur * 4096;
    bf16x8 af[4];
#pragma unroll
    for (int m = 0; m < 4; ++m)
      af[m] = *reinterpret_cast<const bf16x8*>(
          (char*)la + (wm + m * 16 + l15) * 64 + (g16 ^ sx));
    {
      unsigned short* lb = lbq + cur * 2048;
      bf16x8 bfr[2];
#pragma unroll
      for (int n = 0; n < 2; ++n)
        bfr[n] = *reinterpret_cast<const bf16x8*>(
            (char*)lb + (wn + n * 16 + l15) * 64 + (g16 ^ sx));
#pragma unroll
      for (int m = 0; m < 4; ++m)
#pragma unroll
        for (int n = 0; n < 2; ++n) a0[m][n] = mfma16(af[m], bfr[n], a0[m][n]);
    }
    {
      unsigned short* lb = lbk + cur * 2048;
      bf16x8 bfr[2];
#pragma unroll
      for (int n = 0; n < 2; ++n)
        bfr[n] = *reinterpret_cast<const bf16x8*>(
            (char*)lb + (wn + n * 16 + l15) * 64 + (g16 ^ sx));
#pragma unroll
      for (int m = 0; m < 4; ++m)
#pragma unroll
        for (int n = 0; n < 2; ++n) a1[m][n] = mfma16(af[m], bfr[n], a1[m][n]);
    }
    {
      unsigned short* lb = lbv + cur * 2048;
      bf16x8 bfr[2];
#pragma unroll
      for (int n = 0; n < 2; ++n)
        bfr[n] = *reinterpret_cast<const bf16x8*>(
            (char*)lb + (wn + n * 16 + l15) * 64 + (g16 ^ sx));
#pragma unroll
      for (int m = 0; m < 4; ++m)
#pragma unroll
        for (int n = 0; n < 2; ++n) a2[m][n] = mfma16(af[m], bfr[n], a2[m][n]);
    }
    __syncthreads();
  }
#undef STG_QKV

  unsigned short* lw = ls + wave * 2048;
  const int h = (n0 + wn) >> 6;
  const int hd0 = (n0 + wn) & 63;
  const int rb = m0 + wm;
  const int b = rb >> 11;
  const int tb0 = rb & 2047;

#pragma unroll
  for (int mode = 0; mode < 2; ++mode) {
    const float* bias = mode ? bk : bq;
    const float sc = mode ? 1.0f : 0.180336880f;  // 0.125 * log2(e)
    unsigned short* dst = mode ? Ko : Qo;
    WAITLGKM();
#pragma unroll
    for (int m = 0; m < 4; ++m)
#pragma unroll
      for (int n = 0; n < 2; ++n) {
        const float bb = bias[n0 + wn + n * 16 + l15];
        const f32x4 av = mode ? a1[m][n] : a0[m][n];
#pragma unroll
        for (int r = 0; r < 4; ++r)
          lw[(m * 16 + (g << 2) + r) * 32 + n * 16 + l15] =
              f2bf((av[r] + bb) * sc);
      }
    WAITLGKM();
    SCHEDB();
#pragma unroll
    for (int it = 0; it < 4; ++it) {
      const int rr = (lane >> 2) + it * 16;
      const int ck = (lane & 3) * 8;
      uint4 v = *reinterpret_cast<const uint4*>(&lw[rr * 32 + ck]);
      *reinterpret_cast<uint4*>(
          &dst[(((b << 4) + h) * 2048 + tb0 + rr) * 64 + hd0 + ck]) = v;
    }
  }

  WAITLGKM();
#pragma unroll
  for (int m = 0; m < 4; ++m)
#pragma unroll
    for (int n = 0; n < 2; ++n) {
      const float bb = bv[n0 + wn + n * 16 + l15];
      uint2 w;
      w.x = cvtpk(a2[m][n][0] + bb, a2[m][n][1] + bb);
      w.y = cvtpk(a2[m][n][2] + bb, a2[m][n][3] + bb);
      *reinterpret_cast<uint2*>(&lw[(n * 16 + l15) * 64 + m * 16 + (g << 2)]) =
          w;
    }
  WAITLGKM();
  SCHEDB();
#pragma unroll
  for (int it = 0; it < 4; ++it) {
    const int hdr = (lane >> 3) + it * 8;
    const int ck = (lane & 7) * 8;
    uint4 v = *reinterpret_cast<const uint4*>(&lw[hdr * 64 + ck]);
    *reinterpret_cast<uint4*>(
        &Vo[(((b << 4) + h) * 64 + hd0 + hdr) * 2048 + tb0 + ck]) = v;
  }
}

// ---------------- output projection (128x64 tiles, fp32 out + bias) ------
__global__ __launch_bounds__(256) void k_gemm_out(
    const unsigned short* __restrict__ Ctx, const unsigned short* __restrict__ Wo,
    const float* __restrict__ bo, float* __restrict__ Out) {
  __shared__ unsigned short ls[16384];
  unsigned short* la0 = ls;
  unsigned short* lb0 = ls + 8192;
  const int id = blockIdx.x;
  const int xcd = id & 7, s4 = id >> 3;
  const int bx = ((s4 >> 3) & 7) * 2 + (xcd & 1);
  const int by = (s4 & 7) * 4 + (xcd >> 1);
  const int tid = threadIdx.x;
  const int lane = tid & 63, wave = tid >> 6;
  const int l15 = lane & 15, g = lane >> 4;
  const int m0 = by * 128, n0 = bx * 64;
  const int wm = (wave >> 1) * 64, wn = (wave & 1) * 32;
  const int g16 = (g << 4);
  const int sx = (lane & 3) << 4;
  f32x4 acc[4][2] = {};

#define STG_OUT(buf, k0)                                                     \
  {                                                                          \
    _Pragma("unroll") for (int i = 0; i < 2; ++i) {                          \
      const int c = i * 256 + tid;                                           \
      const int row = c >> 2;                                                \
      const int scb = (((c & 3) << 4)) ^ ((row & 3) << 4);                   \
      gload16(Ctx + (m0 + row) * 1024 + (k0) + (scb >> 1),                   \
              (unsigned short*)((char*)(la0 + (buf)*4096) + c * 16));        \
    }                                                                        \
    {                                                                        \
      const int row = tid >> 2;                                              \
      const int scb = (((tid & 3) << 4)) ^ ((row & 3) << 4);                 \
      gload16(Wo + (n0 + row) * 1024 + (k0) + (scb >> 1),                    \
              (unsigned short*)((char*)(lb0 + (buf)*2048) + tid * 16));      \
    }                                                                        \
  }

  STG_OUT(0, 0);
  __syncthreads();

  for (int kt = 0; kt < 32; ++kt) {
    const int cur = kt & 1;
    unsigned short* la = la0 + cur * 4096;
    unsigned short* lb = lb0 + cur * 2048;
    if (kt + 1 < 32) STG_OUT(cur ^ 1, (kt + 1) * 32);
    bf16x8 af[4], bfr[2];
#pragma unroll
    for (int m = 0; m < 4; ++m)
      af[m] = *reinterpret_cast<const bf16x8*>(
          (char*)la + (wm + m * 16 + l15) * 64 + (g16 ^ sx));
#pragma unroll
    for (int n = 0; n < 2; ++n)
      bfr[n] = *reinterpret_cast<const bf16x8*>(
          (char*)lb + (wn + n * 16 + l15) * 64 + (g16 ^ sx));
#pragma unroll
    for (int m = 0; m < 4; ++m)
#pragma unroll
      for (int n = 0; n < 2; ++n)
        acc[m][n] = mfma16(af[m], bfr[n], acc[m][n]);
    __syncthreads();
  }
#undef STG_OUT

  float* lwf = (float*)(ls + wave * 4096);
#pragma unroll
  for (int m = 0; m < 4; ++m)
#pragma unroll
    for (int n = 0; n < 2; ++n) {
      const float bb = bo[n0 + wn + n * 16 + l15];
#pragma unroll
      for (int r = 0; r < 4; ++r)
        lwf[(m * 16 + (g << 2) + r) * 32 + n * 16 + l15] = acc[m][n][r] + bb;
    }
  WAITLGKM();
  SCHEDB();
#pragma unroll
  for (int it = 0; it < 8; ++it) {
    const int rr = (lane >> 3) + it * 8;
    const int ck = (lane & 7) * 4;
    float4 v = *reinterpret_cast<const float4*>(&lwf[rr * 32 + ck]);
    *reinterpret_cast<float4*>(&Out[(m0 + wm + rr) * 1024 + n0 + wn + ck]) = v;
  }
}

// ---------------- causal flash attention (32x32 MFMA, KV-split) ----------
// grid 512 1-D (xcd = bh%8), 512 threads. Waves 0-3 = {B,B,A,A} x 32q
// sweeping KV tiles [0,hB); waves 4-7 = same q sweeping [hB,nt).
// Fixed-max softmax is associative -> O/lsum partials combine exactly.

DEV void attn_stage1(const unsigned short* __restrict__ Kb,
                     const unsigned short* __restrict__ Vb,
                     unsigned short* lk, unsigned short* lv, int kv0,
                     int tid) {
  const int c = tid;              // 0..511 chunks of 16B
  const int row = c >> 3;         // 0..63
  const int scb = ((c & 7) << 4) ^ ((row & 7) << 4);
  gload16(Kb + (kv0 + row) * 64 + (scb >> 1), lk + c * 8);
  gload16(Vb + row * 2048 + kv0 + (scb >> 1), lv + c * 8);
}

// (byte-identical to r15's proven step)
DEV void attn_step32(const unsigned short* lk, const unsigned short* lv,
                     const bf16x8 (&qf)[4], f32x16& O0, f32x16& O1,
                     float& ls, int lane, int sub, int kvg0, int qg,
                     bool diag) {
  const int l31 = lane & 31;
  const int hi = lane >> 5;
  const int h16 = hi << 4;
  const int sw = (l31 & 7) << 4;
  f32x16 st = {};
  PRIO(1);
#pragma unroll
  for (int m = 0; m < 4; ++m) {
    bf16x8 kf = *reinterpret_cast<const bf16x8*>(
        (const char*)lk + (sub * 32 + l31) * 128 + ((m * 32 + h16) ^ sw));
    st = mfma32(kf, qf[m], st);
  }
  PRIO(0);
  if (diag) {
#pragma unroll
    for (int r = 0; r < 16; ++r) {
      const int kvl = (r & 3) + 8 * (r >> 2) + 4 * hi;
      if (kvg0 + sub * 32 + kvl > qg) st[r] = -1e30f;
    }
  }
  float rs = 0.f;
#pragma unroll
  for (int r = 0; r < 16; ++r) {
    float p = exp2f(st[r]);
    st[r] = p;
    rs += p;
  }
  ls += rs;
#pragma unroll
  for (int m2 = 0; m2 < 2; ++m2) {
    unsigned a0 = cvtpk(st[m2 * 8 + 0], st[m2 * 8 + 1]);
    unsigned a1 = cvtpk(st[m2 * 8 + 2], st[m2 * 8 + 3]);
    unsigned a2 = cvtpk(st[m2 * 8 + 4], st[m2 * 8 + 5]);
    unsigned a3 = cvtpk(st[m2 * 8 + 6], st[m2 * 8 + 7]);
    unsigned b0 = a0, b1 = a1, b2 = a2, b3 = a3;
    asm("v_permlane32_swap_b32 %0, %1" : "+v"(a0), "+v"(b0));
    asm("v_permlane32_swap_b32 %0, %1" : "+v"(a1), "+v"(b1));
    asm("v_permlane32_swap_b32 %0, %1" : "+v"(a2), "+v"(b2));
    asm("v_permlane32_swap_b32 %0, %1" : "+v"(a3), "+v"(b3));
    union { unsigned u[4]; bf16x8 v; } pb;
    pb.u[0] = hi ? a2 : a0;
    pb.u[1] = hi ? a3 : a1;
    pb.u[2] = hi ? b2 : b0;
    pb.u[3] = hi ? b3 : b1;
    PRIO(1);
    {
      const int vb = (sub * 64 + m2 * 32 + h16) ^ sw;
      bf16x8 vf0 = *reinterpret_cast<const bf16x8*>(
          (const char*)lv + l31 * 128 + vb);
      O0 = mfma32(vf0, pb.v, O0);
      bf16x8 vf1 = *reinterpret_cast<const bf16x8*>(
          (const char*)lv + (32 + l31) * 128 + vb);
      O1 = mfma32(vf1, pb.v, O1);
    }
    PRIO(0);
  }
}

__global__ __launch_bounds__(512) void k_attn(
    const unsigned short* __restrict__ Q, const unsigned short* __restrict__ K,
    const unsigned short* __restrict__ Vt, unsigned short* __restrict__ Ctx) {
  __shared__ unsigned short lk[4][4096];  // [0,1]=low dbuf, [2,3]=high dbuf
  __shared__ unsigned short lv[4][4096];

  const int tid = threadIdx.x, lane = tid & 63, wave = tid >> 6;
  const int id = blockIdx.x;
  const int xcd = id & 7, r4 = id >> 3;
  const int ip = r4 & 15;
  const int bh = ((r4 >> 4) << 3) + xcd;

  const int qtA = ip;
  const int qtB = 31 - ip;
  const int nt = qtB + 1;          // 17..32
  const int hB = (nt + 1) >> 1;    // 9..16  (low range size; >= high size)

  const bool isHi = wave >= 4;
  const int isA = (wave >> 1) & 1;          // w0,1,4,5=B  w2,3,6,7=A
  const int qt = isA ? qtA : qtB;
  const int qoff = (wave & 1) << 5;
  const int l31 = lane & 31, hi = lane >> 5;
  const int qg = qt * 64 + qoff + l31;

  const unsigned short* Kb = K + bh * 2048 * 64;
  const unsigned short* Vb = Vt + bh * 64 * 2048;

  bf16x8 qf[4];
  {
    const unsigned short* qr = Q + (bh * 2048 + qg) * 64 + (hi << 3);
#pragma unroll
    for (int m = 0; m < 4; ++m)
      qf[m] = *reinterpret_cast<const bf16x8*>(qr + m * 16);
  }

  f32x16 O0 = {}, O1 = {};
  float ls = 0.f;

  // prologue: low tile 0 -> buf0; high tile hB -> buf2
  attn_stage1(Kb, Vb, lk[0], lv[0], 0, tid);
  attn_stage1(Kb, Vb, lk[2], lv[2], hB * 64, tid);

  const int tbase = isHi ? hB : 0;
  const int bsel = isHi ? 2 : 0;

  for (int t = 0; t < hB; ++t) {
    WAITVM(0);  // stage(t) landed (one compute phase old after t=0)
    BAR();      // compute(t-1) done on all waves
    {
      const int nlo = (t + 1 < hB) ? t + 1 : hB - 1;  // clamp: redundant
      attn_stage1(Kb, Vb, lk[(t + 1) & 1], lv[(t + 1) & 1], nlo * 64, tid);
      const int nhi = (hB + t + 1 < nt) ? hB + t + 1 : nt - 1;
      attn_stage1(Kb, Vb, lk[2 + ((t + 1) & 1)], lv[2 + ((t + 1) & 1)],
                  nhi * 64, tid);
    }
    SCHEDB();
    const int gt = tbase + t;
    if (gt <= qt) {
      const unsigned short* lkc = lk[bsel + (t & 1)];
      const unsigned short* lvc = lv[bsel + (t & 1)];
      const bool dg = (gt == qt);
      attn_step32(lkc, lvc, qf, O0, O1, ls, lane, 0, gt * 64, qg, dg);
      attn_step32(lkc, lvc, qf, O0, O1, ls, lane, 1, gt * 64, qg, dg);
    }
  }

  // drain in-flight DMA before buffer reuse / exit (LDS realloc hazard)
  WAITVM(0);
  BAR();

  // high waves publish partials: O -> lv region, ls -> lk tail
  if (isHi) {
    char* base = (char*)lv + (wave - 4) * 8192 + lane * 128;
    union { uint4 u[4]; f32x16 f; } c0, c1;
    c0.f = O0;
    c1.f = O1;
#pragma unroll
    for (int k = 0; k < 4; ++k) {
      *reinterpret_cast<uint4*>(base + k * 16) = c0.u[k];
      *reinterpret_cast<uint4*>(base + 64 + k * 16) = c1.u[k];
    }
    ((float*)((char*)lk + 24576))[(wave - 4) * 64 + lane] = ls;
    WAITLGKM();
  }
  BAR();

  if (!isHi) {
    // combine partner partials
    char* pbase = (char*)lv + wave * 8192 + lane * 128;
    union { uint4 u[4]; f32x16 f; } c0, c1;
#pragma unroll
    for (int k = 0; k < 4; ++k) {
      c0.u[k] = *reinterpret_cast<const uint4*>(pbase + k * 16);
      c1.u[k] = *reinterpret_cast<const uint4*>(pbase + 64 + k * 16);
    }
    O0 += c0.f;
    O1 += c1.f;
    ls += ((const float*)((char*)lk + 24576))[wave * 64 + lane];

    // normalize + pack (r15-proven epilogue)
    float lt = ls + __shfl_xor(ls, 32);
    const float inv = 1.f / lt;
    char* lw = (char*)lk + wave * 4608;

#pragma unroll
    for (int r2 = 0; r2 < 4; ++r2) {
      const int d0 = 8 * r2 + 4 * hi;
      uint2 w;
      w.x = cvtpk(O0[4 * r2] * inv, O0[4 * r2 + 1] * inv);
      w.y = cvtpk(O0[4 * r2 + 2] * inv, O0[4 * r2 + 3] * inv);
      *reinterpret_cast<uint2*>(lw + l31 * 144 + d0 * 2) = w;
    }
#pragma unroll
    for (int r2 = 0; r2 < 4; ++r2) {
      const int d0 = 32 + 8 * r2 + 4 * hi;
      uint2 w;
      w.x = cvtpk(O1[4 * r2] * inv, O1[4 * r2 + 1] * inv);
      w.y = cvtpk(O1[4 * r2 + 2] * inv, O1[4 * r2 + 3] * inv);
      *reinterpret_cast<uint2*>(lw + l31 * 144 + d0 * 2) = w;
    }
    WAITLGKM();
    SCHEDB();

    const int row = lane >> 1, half = lane & 1;
    const int qg2 = qt * 64 + qoff + row;
    const int b = bh >> 4, hh = bh & 15;
#pragma unroll
    for (int k = 0; k < 4; ++k) {
      uint4 v =
          *reinterpret_cast<const uint4*>(lw + row * 144 + half * 64 + k * 16);
      *reinterpret_cast<uint4*>(
          &Ctx[(b * 2048 + qg2) * 1024 + hh * 64 + half * 32 + k * 8]) = v;
    }
  }
}

// ---------------- launch ----------------
extern "C" void kernel_launch(void* const* d_in, const int* in_sizes, int n_in,
                              void* d_out, int out_size, void* d_ws,
                              size_t ws_size, hipStream_t stream) {
  const float* x = (const float*)d_in[0];
  const float* Wq = (const float*)d_in[1];
  const float* bq = (const float*)d_in[2];
  const float* Wk = (const float*)d_in[3];
  const float* bk = (const float*)d_in[4];
  const float* Wv = (const float*)d_in[5];
  const float* bv = (const float*)d_in[6];
  const float* Wo = (const float*)d_in[7];
  const float* bo = (const float*)d_in[8];
  float* out = (float*)d_out;

  char* ws = (char*)d_ws;
  unsigned short* xb = (unsigned short*)(ws);                    // 8 MB
  unsigned short* wqb = (unsigned short*)(ws + (8u << 20));      // 2 MB
  unsigned short* wkb = (unsigned short*)(ws + (10u << 20));
  unsigned short* wvb = (unsigned short*)(ws + (12u << 20));
  unsigned short* wob = (unsigned short*)(ws + (14u << 20));
  unsigned short* Qb = (unsigned short*)(ws + (16u << 20));      // 8 MB
  unsigned short* Kb = (unsigned short*)(ws + (24u << 20));      // 8 MB
  unsigned short* Vtb = (unsigned short*)(ws + (32u << 20));     // 8 MB
  unsigned short* Ctx = (unsigned short*)(ws + (40u << 20));     // 8 MB

  k_cvt_all<<<8192, 256, 0, stream>>>(x, Wq, Wk, Wv, Wo, xb);

  k_gemm_qkv<<<512, 256, 0, stream>>>(xb, wqb, wkb, wvb, bq, bk, bv,
                                      Qb, Kb, Vtb);
  k_attn<<<512, 512, 0, stream>>>(Qb, Kb, Vtb, Ctx);
  k_gemm_out<<<512, 256, 0, stream>>>(Ctx, wob, bo, out);
}

// Round 17
// 106.387 us; speedup vs baseline: 1.3276x; 1.1997x over previous
//
#include <hip/hip_runtime.h>

// Fused MHA: x->QKV proj (bf16 MFMA) -> causal flash attn -> O proj.
// B=2, T=2048, D=1024, H=16, HD=64.
// Round 17: REVERT to r14 (best known: fused QKV + r13 attn KVBLK=128 +
// r10 out). 32x32 attn direction falsified (r15/r16). One micro: skip the
// redundant clamped re-stage on the last attn iteration (uniform branch).

#define DEV __device__ __forceinline__

typedef __attribute__((ext_vector_type(8))) __bf16 bf16x8;
typedef __attribute__((ext_vector_type(4))) float f32x4;

DEV unsigned short f2bf(float f) {
  union { float f; unsigned u; } c;
  c.f = f;
  unsigned u = c.u + 0x7FFFu + ((c.u >> 16) & 1u);  // RTNE
  return (unsigned short)(u >> 16);
}

DEV unsigned cvtpk(float lo, float hi) {
  unsigned r;
  asm("v_cvt_pk_bf16_f32 %0, %1, %2" : "=v"(r) : "v"(lo), "v"(hi));
  return r;
}

DEV void gload16(const unsigned short* g, unsigned short* l) {
  __builtin_amdgcn_global_load_lds(
      (const __attribute__((address_space(1))) unsigned int*)g,
      (__attribute__((address_space(3))) unsigned int*)l, 16, 0, 0);
}

DEV f32x4 mfma16(bf16x8 a, bf16x8 b, f32x4 c) {
  return __builtin_amdgcn_mfma_f32_16x16x32_bf16(a, b, c, 0, 0, 0);
}

#define WAITVM(n) asm volatile("s_waitcnt vmcnt(" #n ")" ::: "memory")
#define WAITLGKM() asm volatile("s_waitcnt lgkmcnt(0)" ::: "memory")
#define BAR() __builtin_amdgcn_s_barrier()
#define SCHEDB() __builtin_amdgcn_sched_barrier(0)
#define PRIO(n) __builtin_amdgcn_s_setprio(n)

// ---------------- fp32 -> bf16 convert (all 5 tensors, one launch) -------
__global__ __launch_bounds__(256) void k_cvt_all(
    const float* __restrict__ x, const float* __restrict__ wq,
    const float* __restrict__ wk, const float* __restrict__ wv,
    const float* __restrict__ wo, unsigned short* __restrict__ dst) {
  int i = blockIdx.x * blockDim.x + threadIdx.x;  // float4 index
  const float* s;
  int off;
  if (i < 1048576) {
    s = x; off = i;
  } else {
    int j = i - 1048576;
    int w = j >> 18;
    off = j & 262143;
    s = (w == 0) ? wq : (w == 1) ? wk : (w == 2) ? wv : wo;
  }
  float4 v = reinterpret_cast<const float4*>(s)[off];
  uint2 o;
  o.x = (unsigned)f2bf(v.x) | ((unsigned)f2bf(v.y) << 16);
  o.y = (unsigned)f2bf(v.z) | ((unsigned)f2bf(v.w) << 16);
  reinterpret_cast<uint2*>(dst)[i] = o;
}

// ---------------- FUSED QKV projection (128x64 tiles, 3 modes) ----------
// grid: 512 1-D. xcd = (by&3)*2 + (bx&1). X tile staged ONCE per K-iter,
// shared by Q/K/V MFMAs.
__global__ __launch_bounds__(256) void k_gemm_qkv(
    const unsigned short* __restrict__ X, const unsigned short* __restrict__ Wq,
    const unsigned short* __restrict__ Wk, const unsigned short* __restrict__ Wv,
    const float* __restrict__ bq, const float* __restrict__ bk,
    const float* __restrict__ bv, unsigned short* __restrict__ Qo,
    unsigned short* __restrict__ Ko, unsigned short* __restrict__ Vo) {
  __shared__ unsigned short ls[20480];  // X 2x4096 | Wq 2x2048 | Wk | Wv
  unsigned short* la0 = ls;
  unsigned short* lbq = ls + 8192;
  unsigned short* lbk = ls + 12288;
  unsigned short* lbv = ls + 16384;

  const int id = blockIdx.x;
  const int xcd = id & 7, s4 = id >> 3;
  const int bx = ((s4 >> 3) & 7) * 2 + (xcd & 1);  // 0..15
  const int by = (s4 & 7) * 4 + (xcd >> 1);        // 0..31
  const int m0 = by * 128, n0 = bx * 64;

  const int tid = threadIdx.x;
  const int lane = tid & 63, wave = tid >> 6;
  const int l15 = lane & 15, g = lane >> 4;
  const int wm = (wave >> 1) * 64, wn = (wave & 1) * 32;
  const int g16 = g << 4;
  const int sx = (lane & 3) << 4;

  f32x4 a0[4][2] = {}, a1[4][2] = {}, a2[4][2] = {};

#define STG_QKV(buf, k0)                                                     \
  {                                                                          \
    _Pragma("unroll") for (int i = 0; i < 2; ++i) {                          \
      const int c = i * 256 + tid;                                           \
      const int row = c >> 2;                                                \
      const int scb = ((c & 3) << 4) ^ ((row & 3) << 4);                     \
      gload16(X + (m0 + row) * 1024 + (k0) + (scb >> 1),                     \
              (unsigned short*)((char*)(la0 + (buf)*4096) + c * 16));        \
    }                                                                        \
    {                                                                        \
      const int row = tid >> 2;                                              \
      const int scb = ((tid & 3) << 4) ^ ((row & 3) << 4);                   \
      const int go = (n0 + row) * 1024 + (k0) + (scb >> 1);                  \
      gload16(Wq + go,                                                       \
              (unsigned short*)((char*)(lbq + (buf)*2048) + tid * 16));      \
      gload16(Wk + go,                                                       \
              (unsigned short*)((char*)(lbk + (buf)*2048) + tid * 16));      \
      gload16(Wv + go,                                                       \
              (unsigned short*)((char*)(lbv + (buf)*2048) + tid * 16));      \
    }                                                                        \
  }

  STG_QKV(0, 0);
  __syncthreads();

  for (int kt = 0; kt < 32; ++kt) {
    const int cur = kt & 1;
    if (kt + 1 < 32) STG_QKV(cur ^ 1, (kt + 1) * 32);
    unsigned short* la = la0 + cur * 4096;
    bf16x8 af[4];
#pragma unroll
    for (int m = 0; m < 4; ++m)
      af[m] = *reinterpret_cast<const bf16x8*>(
          (char*)la + (wm + m * 16 + l15) * 64 + (g16 ^ sx));
    {
      unsigned short* lb = lbq + cur * 2048;
      bf16x8 bfr[2];
#pragma unroll
      for (int n = 0; n < 2; ++n)
        bfr[n] = *reinterpret_cast<const bf16x8*>(
            (char*)lb + (wn + n * 16 + l15) * 64 + (g16 ^ sx));
#pragma unroll
      for (int m = 0; m < 4; ++m)
#pragma unroll
        for (int n = 0; n < 2; ++n) a0[m][n] = mfma16(af[m], bfr[n], a0[m][n]);
    }
    {
      unsigned short* lb = lbk + cur * 2048;
      bf16x8 bfr[2];
#pragma unroll
      for (int n = 0; n < 2; ++n)
        bfr[n] = *reinterpret_cast<const bf16x8*>(
            (char*)lb + (wn + n * 16 + l15) * 64 + (g16 ^ sx));
#pragma unroll
      for (int m = 0; m < 4; ++m)
#pragma unroll
        for (int n = 0; n < 2; ++n) a1[m][n] = mfma16(af[m], bfr[n], a1[m][n]);
    }
    {
      unsigned short* lb = lbv + cur * 2048;
      bf16x8 bfr[2];
#pragma unroll
      for (int n = 0; n < 2; ++n)
        bfr[n] = *reinterpret_cast<const bf16x8*>(
            (char*)lb + (wn + n * 16 + l15) * 64 + (g16 ^ sx));
#pragma unroll
      for (int m = 0; m < 4; ++m)
#pragma unroll
        for (int n = 0; n < 2; ++n) a2[m][n] = mfma16(af[m], bfr[n], a2[m][n]);
    }
    __syncthreads();
  }
#undef STG_QKV

  // ---- epilogues (per-wave 4KB lw; modes sequential with lgkm fences) ----
  unsigned short* lw = ls + wave * 2048;
  const int h = (n0 + wn) >> 6;
  const int hd0 = (n0 + wn) & 63;       // 0 or 32
  const int rb = m0 + wm;
  const int b = rb >> 11;
  const int tb0 = rb & 2047;

  // Q (scaled) then K: lw[64 t][32 hd]
#pragma unroll
  for (int mode = 0; mode < 2; ++mode) {
    const float* bias = mode ? bk : bq;
    const float sc = mode ? 1.0f : 0.180336880f;  // 0.125 * log2(e)
    unsigned short* dst = mode ? Ko : Qo;
    WAITLGKM();  // prior mode's lw reads complete before overwrite
#pragma unroll
    for (int m = 0; m < 4; ++m)
#pragma unroll
      for (int n = 0; n < 2; ++n) {
        const float bb = bias[n0 + wn + n * 16 + l15];
        const f32x4 av = mode ? a1[m][n] : a0[m][n];
#pragma unroll
        for (int r = 0; r < 4; ++r)
          lw[(m * 16 + (g << 2) + r) * 32 + n * 16 + l15] =
              f2bf((av[r] + bb) * sc);
      }
    WAITLGKM();
    SCHEDB();
#pragma unroll
    for (int it = 0; it < 4; ++it) {
      const int rr = (lane >> 2) + it * 16;
      const int ck = (lane & 3) * 8;
      uint4 v = *reinterpret_cast<const uint4*>(&lw[rr * 32 + ck]);
      *reinterpret_cast<uint4*>(
          &dst[(((b << 4) + h) * 2048 + tb0 + rr) * 64 + hd0 + ck]) = v;
    }
  }

  // V^T: lw[32 hd][64 t]
  WAITLGKM();
#pragma unroll
  for (int m = 0; m < 4; ++m)
#pragma unroll
    for (int n = 0; n < 2; ++n) {
      const float bb = bv[n0 + wn + n * 16 + l15];
      uint2 w;
      w.x = cvtpk(a2[m][n][0] + bb, a2[m][n][1] + bb);
      w.y = cvtpk(a2[m][n][2] + bb, a2[m][n][3] + bb);
      *reinterpret_cast<uint2*>(&lw[(n * 16 + l15) * 64 + m * 16 + (g << 2)]) =
          w;
    }
  WAITLGKM();
  SCHEDB();
#pragma unroll
  for (int it = 0; it < 4; ++it) {
    const int hdr = (lane >> 3) + it * 8;
    const int ck = (lane & 7) * 8;
    uint4 v = *reinterpret_cast<const uint4*>(&lw[hdr * 64 + ck]);
    *reinterpret_cast<uint4*>(
        &Vo[(((b << 4) + h) * 64 + hd0 + hdr) * 2048 + tb0 + ck]) = v;
  }
}

// ---------------- output projection (128x64 tiles, fp32 out + bias) ------
// grid: 512 1-D. xcd = (y&3)*2 + (x&1). (r10 version)
__global__ __launch_bounds__(256) void k_gemm_out(
    const unsigned short* __restrict__ Ctx, const unsigned short* __restrict__ Wo,
    const float* __restrict__ bo, float* __restrict__ Out) {
  __shared__ unsigned short ls[16384];
  unsigned short* la0 = ls;
  unsigned short* lb0 = ls + 8192;
  const int id = blockIdx.x;
  const int xcd = id & 7, s4 = id >> 3;            // s4: 0..63
  const int bx = ((s4 >> 3) & 7) * 2 + (xcd & 1);  // 0..15
  const int by = (s4 & 7) * 4 + (xcd >> 1);        // 0..31
  const int tid = threadIdx.x;
  const int lane = tid & 63, wave = tid >> 6;
  const int l15 = lane & 15, g = lane >> 4;
  const int m0 = by * 128, n0 = bx * 64;
  const int wm = (wave >> 1) * 64, wn = (wave & 1) * 32;
  const int g16 = (g << 4);
  const int sx = (lane & 3) << 4;
  f32x4 acc[4][2] = {};

#define STG_OUT(buf, k0)                                                     \
  {                                                                          \
    _Pragma("unroll") for (int i = 0; i < 2; ++i) {                          \
      const int c = i * 256 + tid;                                           \
      const int row = c >> 2;                                                \
      const int scb = (((c & 3) << 4)) ^ ((row & 3) << 4);                   \
      gload16(Ctx + (m0 + row) * 1024 + (k0) + (scb >> 1),                   \
              (unsigned short*)((char*)(la0 + (buf)*4096) + c * 16));        \
    }                                                                        \
    {                                                                        \
      const int row = tid >> 2;                                              \
      const int scb = (((tid & 3) << 4)) ^ ((row & 3) << 4);                 \
      gload16(Wo + (n0 + row) * 1024 + (k0) + (scb >> 1),                    \
              (unsigned short*)((char*)(lb0 + (buf)*2048) + tid * 16));      \
    }                                                                        \
  }

  STG_OUT(0, 0);
  __syncthreads();

  for (int kt = 0; kt < 32; ++kt) {
    const int cur = kt & 1;
    unsigned short* la = la0 + cur * 4096;
    unsigned short* lb = lb0 + cur * 2048;
    if (kt + 1 < 32) STG_OUT(cur ^ 1, (kt + 1) * 32);
    bf16x8 af[4], bfr[2];
#pragma unroll
    for (int m = 0; m < 4; ++m)
      af[m] = *reinterpret_cast<const bf16x8*>(
          (char*)la + (wm + m * 16 + l15) * 64 + (g16 ^ sx));
#pragma unroll
    for (int n = 0; n < 2; ++n)
      bfr[n] = *reinterpret_cast<const bf16x8*>(
          (char*)lb + (wn + n * 16 + l15) * 64 + (g16 ^ sx));
#pragma unroll
    for (int m = 0; m < 4; ++m)
#pragma unroll
      for (int n = 0; n < 2; ++n)
        acc[m][n] = mfma16(af[m], bfr[n], acc[m][n]);
    __syncthreads();
  }
#undef STG_OUT

  float* lwf = (float*)(ls + wave * 4096);
#pragma unroll
  for (int m = 0; m < 4; ++m)
#pragma unroll
    for (int n = 0; n < 2; ++n) {
      const float bb = bo[n0 + wn + n * 16 + l15];
#pragma unroll
      for (int r = 0; r < 4; ++r)
        lwf[(m * 16 + (g << 2) + r) * 32 + n * 16 + l15] = acc[m][n][r] + bb;
    }
  WAITLGKM();
  SCHEDB();
#pragma unroll
  for (int it = 0; it < 8; ++it) {
    const int rr = (lane >> 3) + it * 8;
    const int ck = (lane & 7) * 4;
    float4 v = *reinterpret_cast<const float4*>(&lwf[rr * 32 + ck]);
    *reinterpret_cast<float4*>(&Out[(m0 + wm + rr) * 1024 + n0 + wn + ck]) = v;
  }
}

// ---------------- causal flash attention (8-wave split-pair, KVBLK=128) --
// grid: 512 1-D, xcd = bh%8. Per iter: ONE vmcnt(0) drain + ONE barrier,
// then 2 sub-steps of 64 kv. (r13 structure, proven 45.4us.)

DEV void attn_stage128(const unsigned short* __restrict__ Kb,
                       const unsigned short* __restrict__ Vb,
                       unsigned short* lk, unsigned short* lv, int kv0,
                       int tid) {
#pragma unroll
  for (int i = 0; i < 2; ++i) {
    const int c = i * 512 + tid;            // 0..1023 chunks of 16B
    const int krow = c >> 3;                // 0..127
    const int kscb = ((c & 7) << 4) ^ ((krow & 7) << 4);
    gload16(Kb + (kv0 + krow) * 64 + (kscb >> 1),
            (unsigned short*)((char*)lk + c * 16));
    const int vrow = c >> 4;                // hd 0..63
    const int vscb = ((c & 15) << 4) ^ ((vrow & 7) << 4);
    gload16(Vb + vrow * 2048 + kv0 + (vscb >> 1),
            (unsigned short*)((char*)lv + c * 16));
  }
}

DEV void attn_step(const unsigned short* lk128, int s,
                   const unsigned short* lv128,
                   unsigned short (&lp)[16][64], const bf16x8 (&qf)[2],
                   f32x4 (&o)[4], float& lsum, int lane, int qloc, bool diag) {
  const int g = lane >> 4;
  const int l15 = lane & 15;
  f32x4 st[4];
  PRIO(1);
#pragma unroll
  for (int n = 0; n < 4; ++n) {
    f32x4 z = {};
    const int row = n * 16 + l15;
    const int sw = (row & 7) << 4;
#pragma unroll
    for (int kk = 0; kk < 2; ++kk) {
      bf16x8 kf = *reinterpret_cast<const bf16x8*>(
          (char*)lk128 + (s * 64 + row) * 128 + ((kk * 64 + (g << 4)) ^ sw));
      z = mfma16(kf, qf[kk], z);
    }
    st[n] = z;
  }
  PRIO(0);
  if (diag) {
#pragma unroll
    for (int n = 0; n < 4; ++n)
#pragma unroll
      for (int r = 0; r < 4; ++r)
        if (n * 16 + g * 4 + r > qloc) st[n][r] = -1e30f;
  }
  float rs = 0.f;
#pragma unroll
  for (int n = 0; n < 4; ++n)
#pragma unroll
    for (int r = 0; r < 4; ++r) {
      float p = exp2f(st[n][r]);
      st[n][r] = p;
      rs += p;
    }
  lsum += rs;
  const int psw = (l15 & 7) << 4;
#pragma unroll
  for (int n = 0; n < 4; ++n) {
    uint2 w;
    w.x = cvtpk(st[n][0], st[n][1]);
    w.y = cvtpk(st[n][2], st[n][3]);
    *reinterpret_cast<uint2*>(
        (char*)lp + l15 * 128 + (((n << 5) | (g << 3)) ^ psw)) = w;
  }
  WAITLGKM();
  SCHEDB();
  bf16x8 pb[2];
  pb[0] = *reinterpret_cast<const bf16x8*>(
      (char*)lp + l15 * 128 + (((g << 4)) ^ psw));
  pb[1] = *reinterpret_cast<const bf16x8*>(
      (char*)lp + l15 * 128 + ((64 + (g << 4)) ^ psw));
  PRIO(1);
#pragma unroll
  for (int h = 0; h < 4; ++h) {
    const int vr = h * 16 + l15;
    const int sw = (vr & 7) << 4;
#pragma unroll
    for (int kk = 0; kk < 2; ++kk) {
      bf16x8 vf = *reinterpret_cast<const bf16x8*>(
          (char*)lv128 + vr * 256 + ((s * 128 + kk * 64 + (g << 4)) ^ sw));
      o[h] = mfma16(vf, pb[kk], o[h]);
    }
  }
  PRIO(0);
}

DEV void attn_epi(unsigned short* __restrict__ Ctx,
                  unsigned short (&lp)[16][64], const f32x4 (&o)[4],
                  float lsum, int b, int hh, int qbase, int lane) {
  float lt = lsum;
  lt += __shfl_xor(lt, 16);
  lt += __shfl_xor(lt, 32);
  const float inv = 1.f / lt;
  const int g = lane >> 4;
  const int l15 = lane & 15;
  const int psw = (l15 & 7) << 4;
#pragma unroll
  for (int h = 0; h < 4; ++h) {
    uint2 w;
    w.x = cvtpk(o[h][0] * inv, o[h][1] * inv);
    w.y = cvtpk(o[h][2] * inv, o[h][3] * inv);
    *reinterpret_cast<uint2*>(
        (char*)lp + l15 * 128 + (((h << 5) | (g << 3)) ^ psw)) = w;
  }
  WAITLGKM();
  SCHEDB();
#pragma unroll
  for (int it = 0; it < 2; ++it) {
    const int q = (lane >> 3) + it * 8;
    const int blk = (lane & 7) ^ (q & 7);
    uint4 v = *reinterpret_cast<const uint4*>((char*)lp + q * 128 + blk * 16);
    *reinterpret_cast<uint4*>(
        &Ctx[(b * 2048 + qbase + q) * 1024 + hh * 64 + ((lane & 7) << 3)]) = v;
  }
}

__global__ __launch_bounds__(512) void k_attn(
    const unsigned short* __restrict__ Q, const unsigned short* __restrict__ K,
    const unsigned short* __restrict__ Vt, unsigned short* __restrict__ Ctx) {
  __shared__ unsigned short lk[2][8192];    // K [128][64], double buffer
  __shared__ unsigned short lv[2][8192];    // V^T [64][128], double buffer
  __shared__ unsigned short lp[8][16][64];  // per-wave, XOR-swizzled

  const int tid = threadIdx.x, lane = tid & 63, wave = tid >> 6;
  const int id = blockIdx.x;
  const int xcd = id & 7, r4 = id >> 3;  // r4: 0..63
  const int ip = r4 & 15;
  const int bh = ((r4 >> 4) << 3) + xcd;

  const int qtA = ip;
  const int qtB = 31 - ip;
  const int nb = (qtB >> 1) + 1;

  const bool isB = wave < 4;
  const int wv4 = wave & 3;
  const int qt = isB ? qtB : qtA;

  const unsigned short* Kb = K + bh * 2048 * 64;
  const unsigned short* Vb = Vt + bh * 64 * 2048;

  bf16x8 qf[2];
  {
    const unsigned short* qr =
        Q + (bh * 2048 + qt * 64 + wv4 * 16 + (lane & 15)) * 64 +
        ((lane >> 4) << 3);
    qf[0] = *reinterpret_cast<const bf16x8*>(qr);
    qf[1] = *reinterpret_cast<const bf16x8*>(qr + 32);
  }

  f32x4 o[4] = {};
  float lsum = 0.f;
  const int qloc = wv4 * 16 + (lane & 15);

  attn_stage128(Kb, Vb, lk[0], lv[0], 0, tid);

  for (int t = 0; t < nb; ++t) {
    WAITVM(0);  // stage(t) fully landed (L2-resident, short drain)
    BAR();      // all waves done with compute(t-1); stage(t) visible
    if (t + 1 < nb)  // uniform branch; skip redundant tail re-stage
      attn_stage128(Kb, Vb, lk[(t + 1) & 1], lv[(t + 1) & 1], (t + 1) * 128,
                    tid);
    SCHEDB();
    const unsigned short* lkc = lk[t & 1];
    const unsigned short* lvc = lv[t & 1];
#pragma unroll
    for (int s = 0; s < 2; ++s) {
      const int sub = 2 * t + s;
      if (sub <= qt)
        attn_step(lkc, s, lvc, lp[wave], qf, o, lsum, lane, qloc, sub == qt);
    }
  }

  // Drain any in-flight global_load_lds before workgroup exit (LDS is
  // reallocated at endpgm; late DMA would corrupt the next workgroup).
  WAITVM(0);

  const int b = bh >> 4, hh = bh & 15;
  attn_epi(Ctx, lp[wave], o, lsum, b, hh, qt * 64 + wv4 * 16, lane);
}

// ---------------- launch ----------------
extern "C" void kernel_launch(void* const* d_in, const int* in_sizes, int n_in,
                              void* d_out, int out_size, void* d_ws,
                              size_t ws_size, hipStream_t stream) {
  const float* x = (const float*)d_in[0];
  const float* Wq = (const float*)d_in[1];
  const float* bq = (const float*)d_in[2];
  const float* Wk = (const float*)d_in[3];
  const float* bk = (const float*)d_in[4];
  const float* Wv = (const float*)d_in[5];
  const float* bv = (const float*)d_in[6];
  const float* Wo = (const float*)d_in[7];
  const float* bo = (const float*)d_in[8];
  float* out = (float*)d_out;

  char* ws = (char*)d_ws;
  unsigned short* xb = (unsigned short*)(ws);                    // 8 MB
  unsigned short* wqb = (unsigned short*)(ws + (8u << 20));      // 2 MB
  unsigned short* wkb = (unsigned short*)(ws + (10u << 20));
  unsigned short* wvb = (unsigned short*)(ws + (12u << 20));
  unsigned short* wob = (unsigned short*)(ws + (14u << 20));
  unsigned short* Qb = (unsigned short*)(ws + (16u << 20));      // 8 MB
  unsigned short* Kb = (unsigned short*)(ws + (24u << 20));      // 8 MB
  unsigned short* Vtb = (unsigned short*)(ws + (32u << 20));     // 8 MB
  unsigned short* Ctx = (unsigned short*)(ws + (40u << 20));     // 8 MB

  k_cvt_all<<<8192, 256, 0, stream>>>(x, Wq, Wk, Wv, Wo, xb);

  k_gemm_qkv<<<512, 256, 0, stream>>>(xb, wqb, wkb, wvb, bq, bk, bv,
                                      Qb, Kb, Vtb);
  k_attn<<<512, 512, 0, stream>>>(Qb, Kb, Vtb, Ctx);
  k_gemm_out<<<512, 256, 0, stream>>>(Ctx, wob, bo, out);
}

// Round 18
// 106.074 us; speedup vs baseline: 1.3315x; 1.0030x over previous
//
#include <hip/hip_runtime.h>

// Fused MHA: x->QKV proj (bf16 MFMA) -> causal flash attn -> O proj.
// B=2, T=2048, D=1024, H=16, HD=64.
// Round 18: attn PARITY SPLIT — wave w = (parity w>>2, row-group w&3).
// Waves 0-3 do even 64-kv sub-steps of BOTH q-tiles, waves 4-7 odd ones.
// Per-block critical path 18..34 -> ~17 sub-steps uniformly. Partials
// combined via XOR-swizzled LDS overlay. qkv/out/cvt = r17 unchanged.

#define DEV __device__ __forceinline__

typedef __attribute__((ext_vector_type(8))) __bf16 bf16x8;
typedef __attribute__((ext_vector_type(4))) float f32x4;

DEV unsigned short f2bf(float f) {
  union { float f; unsigned u; } c;
  c.f = f;
  unsigned u = c.u + 0x7FFFu + ((c.u >> 16) & 1u);  // RTNE
  return (unsigned short)(u >> 16);
}

DEV unsigned cvtpk(float lo, float hi) {
  unsigned r;
  asm("v_cvt_pk_bf16_f32 %0, %1, %2" : "=v"(r) : "v"(lo), "v"(hi));
  return r;
}

DEV void gload16(const unsigned short* g, unsigned short* l) {
  __builtin_amdgcn_global_load_lds(
      (const __attribute__((address_space(1))) unsigned int*)g,
      (__attribute__((address_space(3))) unsigned int*)l, 16, 0, 0);
}

DEV f32x4 mfma16(bf16x8 a, bf16x8 b, f32x4 c) {
  return __builtin_amdgcn_mfma_f32_16x16x32_bf16(a, b, c, 0, 0, 0);
}

#define WAITVM(n) asm volatile("s_waitcnt vmcnt(" #n ")" ::: "memory")
#define WAITLGKM() asm volatile("s_waitcnt lgkmcnt(0)" ::: "memory")
#define BAR() __builtin_amdgcn_s_barrier()
#define SCHEDB() __builtin_amdgcn_sched_barrier(0)
#define PRIO(n) __builtin_amdgcn_s_setprio(n)

// ---------------- fp32 -> bf16 convert (all 5 tensors, one launch) -------
__global__ __launch_bounds__(256) void k_cvt_all(
    const float* __restrict__ x, const float* __restrict__ wq,
    const float* __restrict__ wk, const float* __restrict__ wv,
    const float* __restrict__ wo, unsigned short* __restrict__ dst) {
  int i = blockIdx.x * blockDim.x + threadIdx.x;  // float4 index
  const float* s;
  int off;
  if (i < 1048576) {
    s = x; off = i;
  } else {
    int j = i - 1048576;
    int w = j >> 18;
    off = j & 262143;
    s = (w == 0) ? wq : (w == 1) ? wk : (w == 2) ? wv : wo;
  }
  float4 v = reinterpret_cast<const float4*>(s)[off];
  uint2 o;
  o.x = (unsigned)f2bf(v.x) | ((unsigned)f2bf(v.y) << 16);
  o.y = (unsigned)f2bf(v.z) | ((unsigned)f2bf(v.w) << 16);
  reinterpret_cast<uint2*>(dst)[i] = o;
}

// ---------------- FUSED QKV projection (128x64 tiles, 3 modes) ----------
__global__ __launch_bounds__(256) void k_gemm_qkv(
    const unsigned short* __restrict__ X, const unsigned short* __restrict__ Wq,
    const unsigned short* __restrict__ Wk, const unsigned short* __restrict__ Wv,
    const float* __restrict__ bq, const float* __restrict__ bk,
    const float* __restrict__ bv, unsigned short* __restrict__ Qo,
    unsigned short* __restrict__ Ko, unsigned short* __restrict__ Vo) {
  __shared__ unsigned short ls[20480];  // X 2x4096 | Wq 2x2048 | Wk | Wv
  unsigned short* la0 = ls;
  unsigned short* lbq = ls + 8192;
  unsigned short* lbk = ls + 12288;
  unsigned short* lbv = ls + 16384;

  const int id = blockIdx.x;
  const int xcd = id & 7, s4 = id >> 3;
  const int bx = ((s4 >> 3) & 7) * 2 + (xcd & 1);  // 0..15
  const int by = (s4 & 7) * 4 + (xcd >> 1);        // 0..31
  const int m0 = by * 128, n0 = bx * 64;

  const int tid = threadIdx.x;
  const int lane = tid & 63, wave = tid >> 6;
  const int l15 = lane & 15, g = lane >> 4;
  const int wm = (wave >> 1) * 64, wn = (wave & 1) * 32;
  const int g16 = g << 4;
  const int sx = (lane & 3) << 4;

  f32x4 a0[4][2] = {}, a1[4][2] = {}, a2[4][2] = {};

#define STG_QKV(buf, k0)                                                     \
  {                                                                          \
    _Pragma("unroll") for (int i = 0; i < 2; ++i) {                          \
      const int c = i * 256 + tid;                                           \
      const int row = c >> 2;                                                \
      const int scb = ((c & 3) << 4) ^ ((row & 3) << 4);                     \
      gload16(X + (m0 + row) * 1024 + (k0) + (scb >> 1),                     \
              (unsigned short*)((char*)(la0 + (buf)*4096) + c * 16));        \
    }                                                                        \
    {                                                                        \
      const int row = tid >> 2;                                              \
      const int scb = ((tid & 3) << 4) ^ ((row & 3) << 4);                   \
      const int go = (n0 + row) * 1024 + (k0) + (scb >> 1);                  \
      gload16(Wq + go,                                                       \
              (unsigned short*)((char*)(lbq + (buf)*2048) + tid * 16));      \
      gload16(Wk + go,                                                       \
              (unsigned short*)((char*)(lbk + (buf)*2048) + tid * 16));      \
      gload16(Wv + go,                                                       \
              (unsigned short*)((char*)(lbv + (buf)*2048) + tid * 16));      \
    }                                                                        \
  }

  STG_QKV(0, 0);
  __syncthreads();

  for (int kt = 0; kt < 32; ++kt) {
    const int cur = kt & 1;
    if (kt + 1 < 32) STG_QKV(cur ^ 1, (kt + 1) * 32);
    unsigned short* la = la0 + cur * 4096;
    bf16x8 af[4];
#pragma unroll
    for (int m = 0; m < 4; ++m)
      af[m] = *reinterpret_cast<const bf16x8*>(
          (char*)la + (wm + m * 16 + l15) * 64 + (g16 ^ sx));
    {
      unsigned short* lb = lbq + cur * 2048;
      bf16x8 bfr[2];
#pragma unroll
      for (int n = 0; n < 2; ++n)
        bfr[n] = *reinterpret_cast<const bf16x8*>(
            (char*)lb + (wn + n * 16 + l15) * 64 + (g16 ^ sx));
#pragma unroll
      for (int m = 0; m < 4; ++m)
#pragma unroll
        for (int n = 0; n < 2; ++n) a0[m][n] = mfma16(af[m], bfr[n], a0[m][n]);
    }
    {
      unsigned short* lb = lbk + cur * 2048;
      bf16x8 bfr[2];
#pragma unroll
      for (int n = 0; n < 2; ++n)
        bfr[n] = *reinterpret_cast<const bf16x8*>(
            (char*)lb + (wn + n * 16 + l15) * 64 + (g16 ^ sx));
#pragma unroll
      for (int m = 0; m < 4; ++m)
#pragma unroll
        for (int n = 0; n < 2; ++n) a1[m][n] = mfma16(af[m], bfr[n], a1[m][n]);
    }
    {
      unsigned short* lb = lbv + cur * 2048;
      bf16x8 bfr[2];
#pragma unroll
      for (int n = 0; n < 2; ++n)
        bfr[n] = *reinterpret_cast<const bf16x8*>(
            (char*)lb + (wn + n * 16 + l15) * 64 + (g16 ^ sx));
#pragma unroll
      for (int m = 0; m < 4; ++m)
#pragma unroll
        for (int n = 0; n < 2; ++n) a2[m][n] = mfma16(af[m], bfr[n], a2[m][n]);
    }
    __syncthreads();
  }
#undef STG_QKV

  // ---- epilogues (per-wave 4KB lw; modes sequential with lgkm fences) ----
  unsigned short* lw = ls + wave * 2048;
  const int h = (n0 + wn) >> 6;
  const int hd0 = (n0 + wn) & 63;       // 0 or 32
  const int rb = m0 + wm;
  const int b = rb >> 11;
  const int tb0 = rb & 2047;

  // Q (scaled) then K: lw[64 t][32 hd]
#pragma unroll
  for (int mode = 0; mode < 2; ++mode) {
    const float* bias = mode ? bk : bq;
    const float sc = mode ? 1.0f : 0.180336880f;  // 0.125 * log2(e)
    unsigned short* dst = mode ? Ko : Qo;
    WAITLGKM();  // prior mode's lw reads complete before overwrite
#pragma unroll
    for (int m = 0; m < 4; ++m)
#pragma unroll
      for (int n = 0; n < 2; ++n) {
        const float bb = bias[n0 + wn + n * 16 + l15];
        const f32x4 av = mode ? a1[m][n] : a0[m][n];
#pragma unroll
        for (int r = 0; r < 4; ++r)
          lw[(m * 16 + (g << 2) + r) * 32 + n * 16 + l15] =
              f2bf((av[r] + bb) * sc);
      }
    WAITLGKM();
    SCHEDB();
#pragma unroll
    for (int it = 0; it < 4; ++it) {
      const int rr = (lane >> 2) + it * 16;
      const int ck = (lane & 3) * 8;
      uint4 v = *reinterpret_cast<const uint4*>(&lw[rr * 32 + ck]);
      *reinterpret_cast<uint4*>(
          &dst[(((b << 4) + h) * 2048 + tb0 + rr) * 64 + hd0 + ck]) = v;
    }
  }

  // V^T: lw[32 hd][64 t]
  WAITLGKM();
#pragma unroll
  for (int m = 0; m < 4; ++m)
#pragma unroll
    for (int n = 0; n < 2; ++n) {
      const float bb = bv[n0 + wn + n * 16 + l15];
      uint2 w;
      w.x = cvtpk(a2[m][n][0] + bb, a2[m][n][1] + bb);
      w.y = cvtpk(a2[m][n][2] + bb, a2[m][n][3] + bb);
      *reinterpret_cast<uint2*>(&lw[(n * 16 + l15) * 64 + m * 16 + (g << 2)]) =
          w;
    }
  WAITLGKM();
  SCHEDB();
#pragma unroll
  for (int it = 0; it < 4; ++it) {
    const int hdr = (lane >> 3) + it * 8;
    const int ck = (lane & 7) * 8;
    uint4 v = *reinterpret_cast<const uint4*>(&lw[hdr * 64 + ck]);
    *reinterpret_cast<uint4*>(
        &Vo[(((b << 4) + h) * 64 + hd0 + hdr) * 2048 + tb0 + ck]) = v;
  }
}

// ---------------- output projection (128x64 tiles, fp32 out + bias) ------
__global__ __launch_bounds__(256) void k_gemm_out(
    const unsigned short* __restrict__ Ctx, const unsigned short* __restrict__ Wo,
    const float* __restrict__ bo, float* __restrict__ Out) {
  __shared__ unsigned short ls[16384];
  unsigned short* la0 = ls;
  unsigned short* lb0 = ls + 8192;
  const int id = blockIdx.x;
  const int xcd = id & 7, s4 = id >> 3;            // s4: 0..63
  const int bx = ((s4 >> 3) & 7) * 2 + (xcd & 1);  // 0..15
  const int by = (s4 & 7) * 4 + (xcd >> 1);        // 0..31
  const int tid = threadIdx.x;
  const int lane = tid & 63, wave = tid >> 6;
  const int l15 = lane & 15, g = lane >> 4;
  const int m0 = by * 128, n0 = bx * 64;
  const int wm = (wave >> 1) * 64, wn = (wave & 1) * 32;
  const int g16 = (g << 4);
  const int sx = (lane & 3) << 4;
  f32x4 acc[4][2] = {};

#define STG_OUT(buf, k0)                                                     \
  {                                                                          \
    _Pragma("unroll") for (int i = 0; i < 2; ++i) {                          \
      const int c = i * 256 + tid;                                           \
      const int row = c >> 2;                                                \
      const int scb = (((c & 3) << 4)) ^ ((row & 3) << 4);                   \
      gload16(Ctx + (m0 + row) * 1024 + (k0) + (scb >> 1),                   \
              (unsigned short*)((char*)(la0 + (buf)*4096) + c * 16));        \
    }                                                                        \
    {                                                                        \
      const int row = tid >> 2;                                              \
      const int scb = (((tid & 3) << 4)) ^ ((row & 3) << 4);                 \
      gload16(Wo + (n0 + row) * 1024 + (k0) + (scb >> 1),                    \
              (unsigned short*)((char*)(lb0 + (buf)*2048) + tid * 16));      \
    }                                                                        \
  }

  STG_OUT(0, 0);
  __syncthreads();

  for (int kt = 0; kt < 32; ++kt) {
    const int cur = kt & 1;
    unsigned short* la = la0 + cur * 4096;
    unsigned short* lb = lb0 + cur * 2048;
    if (kt + 1 < 32) STG_OUT(cur ^ 1, (kt + 1) * 32);
    bf16x8 af[4], bfr[2];
#pragma unroll
    for (int m = 0; m < 4; ++m)
      af[m] = *reinterpret_cast<const bf16x8*>(
          (char*)la + (wm + m * 16 + l15) * 64 + (g16 ^ sx));
#pragma unroll
    for (int n = 0; n < 2; ++n)
      bfr[n] = *reinterpret_cast<const bf16x8*>(
          (char*)lb + (wn + n * 16 + l15) * 64 + (g16 ^ sx));
#pragma unroll
    for (int m = 0; m < 4; ++m)
#pragma unroll
      for (int n = 0; n < 2; ++n)
        acc[m][n] = mfma16(af[m], bfr[n], acc[m][n]);
    __syncthreads();
  }
#undef STG_OUT

  float* lwf = (float*)(ls + wave * 4096);
#pragma unroll
  for (int m = 0; m < 4; ++m)
#pragma unroll
    for (int n = 0; n < 2; ++n) {
      const float bb = bo[n0 + wn + n * 16 + l15];
#pragma unroll
      for (int r = 0; r < 4; ++r)
        lwf[(m * 16 + (g << 2) + r) * 32 + n * 16 + l15] = acc[m][n][r] + bb;
    }
  WAITLGKM();
  SCHEDB();
#pragma unroll
  for (int it = 0; it < 8; ++it) {
    const int rr = (lane >> 3) + it * 8;
    const int ck = (lane & 7) * 4;
    float4 v = *reinterpret_cast<const float4*>(&lwf[rr * 32 + ck]);
    *reinterpret_cast<float4*>(&Out[(m0 + wm + rr) * 1024 + n0 + wn + ck]) = v;
  }
}

// ---------------- causal flash attention (parity-split, KVBLK=128) -------
// grid: 512 1-D, xcd = bh%8. Wave w: parity s=w>>2, row-group rg=w&3.
// Each wave handles sub-steps of its parity for BOTH q-tiles (B=31-ip,
// A=ip); per-block critical path ~17 sub-steps for every ip. Partials
// (O, lsum) combined across wave pairs (w, w+4) via swizzled LDS overlay.

DEV void attn_stage128(const unsigned short* __restrict__ Kb,
                       const unsigned short* __restrict__ Vb,
                       unsigned short* lk, unsigned short* lv, int kv0,
                       int tid) {
#pragma unroll
  for (int i = 0; i < 2; ++i) {
    const int c = i * 512 + tid;            // 0..1023 chunks of 16B
    const int krow = c >> 3;                // 0..127
    const int kscb = ((c & 7) << 4) ^ ((krow & 7) << 4);
    gload16(Kb + (kv0 + krow) * 64 + (kscb >> 1),
            (unsigned short*)((char*)lk + c * 16));
    const int vrow = c >> 4;                // hd 0..63
    const int vscb = ((c & 15) << 4) ^ ((vrow & 7) << 4);
    gload16(Vb + vrow * 2048 + kv0 + (vscb >> 1),
            (unsigned short*)((char*)lv + c * 16));
  }
}

DEV void attn_step(const unsigned short* lk128, int s,
                   const unsigned short* lv128,
                   unsigned short (&lp)[16][64], const bf16x8 (&qf)[2],
                   f32x4 (&o)[4], float& lsum, int lane, int qloc, bool diag) {
  const int g = lane >> 4;
  const int l15 = lane & 15;
  f32x4 st[4];
  PRIO(1);
#pragma unroll
  for (int n = 0; n < 4; ++n) {
    f32x4 z = {};
    const int row = n * 16 + l15;
    const int sw = (row & 7) << 4;
#pragma unroll
    for (int kk = 0; kk < 2; ++kk) {
      bf16x8 kf = *reinterpret_cast<const bf16x8*>(
          (char*)lk128 + (s * 64 + row) * 128 + ((kk * 64 + (g << 4)) ^ sw));
      z = mfma16(kf, qf[kk], z);
    }
    st[n] = z;
  }
  PRIO(0);
  if (diag) {
#pragma unroll
    for (int n = 0; n < 4; ++n)
#pragma unroll
      for (int r = 0; r < 4; ++r)
        if (n * 16 + g * 4 + r > qloc) st[n][r] = -1e30f;
  }
  float rs = 0.f;
#pragma unroll
  for (int n = 0; n < 4; ++n)
#pragma unroll
    for (int r = 0; r < 4; ++r) {
      float p = exp2f(st[n][r]);
      st[n][r] = p;
      rs += p;
    }
  lsum += rs;
  const int psw = (l15 & 7) << 4;
#pragma unroll
  for (int n = 0; n < 4; ++n) {
    uint2 w;
    w.x = cvtpk(st[n][0], st[n][1]);
    w.y = cvtpk(st[n][2], st[n][3]);
    *reinterpret_cast<uint2*>(
        (char*)lp + l15 * 128 + (((n << 5) | (g << 3)) ^ psw)) = w;
  }
  WAITLGKM();
  SCHEDB();
  bf16x8 pb[2];
  pb[0] = *reinterpret_cast<const bf16x8*>(
      (char*)lp + l15 * 128 + (((g << 4)) ^ psw));
  pb[1] = *reinterpret_cast<const bf16x8*>(
      (char*)lp + l15 * 128 + ((64 + (g << 4)) ^ psw));
  PRIO(1);
#pragma unroll
  for (int h = 0; h < 4; ++h) {
    const int vr = h * 16 + l15;
    const int sw = (vr & 7) << 4;
#pragma unroll
    for (int kk = 0; kk < 2; ++kk) {
      bf16x8 vf = *reinterpret_cast<const bf16x8*>(
          (char*)lv128 + vr * 256 + ((s * 128 + kk * 64 + (g << 4)) ^ sw));
      o[h] = mfma16(vf, pb[kk], o[h]);
    }
  }
  PRIO(0);
}

DEV void attn_epi(unsigned short* __restrict__ Ctx,
                  unsigned short (&lp)[16][64], const f32x4 (&o)[4],
                  float lsum, int b, int hh, int qbase, int lane) {
  float lt = lsum;
  lt += __shfl_xor(lt, 16);
  lt += __shfl_xor(lt, 32);
  const float inv = 1.f / lt;
  const int g = lane >> 4;
  const int l15 = lane & 15;
  const int psw = (l15 & 7) << 4;
#pragma unroll
  for (int h = 0; h < 4; ++h) {
    uint2 w;
    w.x = cvtpk(o[h][0] * inv, o[h][1] * inv);
    w.y = cvtpk(o[h][2] * inv, o[h][3] * inv);
    *reinterpret_cast<uint2*>(
        (char*)lp + l15 * 128 + (((h << 5) | (g << 3)) ^ psw)) = w;
  }
  WAITLGKM();
  SCHEDB();
#pragma unroll
  for (int it = 0; it < 2; ++it) {
    const int q = (lane >> 3) + it * 8;
    const int blk = (lane & 7) ^ (q & 7);
    uint4 v = *reinterpret_cast<const uint4*>((char*)lp + q * 128 + blk * 16);
    *reinterpret_cast<uint4*>(
        &Ctx[(b * 2048 + qbase + q) * 1024 + hh * 64 + ((lane & 7) << 3)]) = v;
  }
}

__global__ __launch_bounds__(512) void k_attn(
    const unsigned short* __restrict__ Q, const unsigned short* __restrict__ K,
    const unsigned short* __restrict__ Vt, unsigned short* __restrict__ Ctx) {
  __shared__ unsigned short lk[2][8192];    // K [128][64], double buffer
  __shared__ unsigned short lv[2][8192];    // V^T [64][128], double buffer
  __shared__ unsigned short lp[8][16][64];  // per-wave, XOR-swizzled

  const int tid = threadIdx.x, lane = tid & 63, wave = tid >> 6;
  const int id = blockIdx.x;
  const int xcd = id & 7, r4 = id >> 3;  // r4: 0..63
  const int ip = r4 & 15;
  const int bh = ((r4 >> 4) << 3) + xcd;

  const int qtA = ip;
  const int qtB = 31 - ip;
  const int nb = (qtB >> 1) + 1;

  const int s = wave >> 2;     // kv-parity of this wave
  const int rg = wave & 3;     // q row-group (16 rows) within 64-row tile
  const int l15 = lane & 15;
  const int qloc = rg * 16 + l15;

  const unsigned short* Kb = K + bh * 2048 * 64;
  const unsigned short* Vb = Vt + bh * 64 * 2048;

  bf16x8 qfB[2], qfA[2];
  {
    const unsigned short* qr =
        Q + (bh * 2048 + qtB * 64 + rg * 16 + l15) * 64 + ((lane >> 4) << 3);
    qfB[0] = *reinterpret_cast<const bf16x8*>(qr);
    qfB[1] = *reinterpret_cast<const bf16x8*>(qr + 32);
    qr = Q + (bh * 2048 + qtA * 64 + rg * 16 + l15) * 64 + ((lane >> 4) << 3);
    qfA[0] = *reinterpret_cast<const bf16x8*>(qr);
    qfA[1] = *reinterpret_cast<const bf16x8*>(qr + 32);
  }

  f32x4 oB[4] = {}, oA[4] = {};
  float lsB = 0.f, lsA = 0.f;

  attn_stage128(Kb, Vb, lk[0], lv[0], 0, tid);

  for (int t = 0; t < nb; ++t) {
    WAITVM(0);  // stage(t) fully landed (L2-resident, short drain)
    BAR();      // all waves done with compute(t-1); stage(t) visible
    if (t + 1 < nb)  // uniform branch; no redundant tail re-stage
      attn_stage128(Kb, Vb, lk[(t + 1) & 1], lv[(t + 1) & 1], (t + 1) * 128,
                    tid);
    SCHEDB();
    const unsigned short* lkc = lk[t & 1];
    const unsigned short* lvc = lv[t & 1];
    const int sub = 2 * t + s;  // this wave's parity sub-step
    if (sub <= qtB)
      attn_step(lkc, s, lvc, lp[wave], qfB, oB, lsB, lane, qloc, sub == qtB);
    if (sub <= qtA)
      attn_step(lkc, s, lvc, lp[wave], qfA, oA, lsA, lane, qloc, sub == qtA);
  }

  // Drain in-flight DMA before overlaying lk and before endpgm.
  WAITVM(0);
  BAR();

  // waves 4-7 publish partials into lk overlay (XOR-swizzled, conflict-free)
  if (s == 1) {
    char* base = (char*)lk + (wave - 4) * 8192 + lane * 128;
    const int lx = lane & 7;
#pragma unroll
    for (int h = 0; h < 4; ++h) {
      *reinterpret_cast<f32x4*>(base + ((h ^ lx) << 4)) = oB[h];
      *reinterpret_cast<f32x4*>(base + (((4 + h) ^ lx) << 4)) = oA[h];
    }
    float2 lsp;
    lsp.x = lsB;
    lsp.y = lsA;
    *reinterpret_cast<float2*>((char*)lv + ((wave - 4) * 64 + lane) * 8) = lsp;
    WAITLGKM();  // ds_writes visible before the barrier
  }
  BAR();

  if (s == 0) {
    char* base = (char*)lk + wave * 8192 + lane * 128;
    const int lx = lane & 7;
#pragma unroll
    for (int h = 0; h < 4; ++h) {
      f32x4 pB = *reinterpret_cast<const f32x4*>(base + ((h ^ lx) << 4));
      f32x4 pA = *reinterpret_cast<const f32x4*>(base + (((4 + h) ^ lx) << 4));
      oB[h] += pB;
      oA[h] += pA;
    }
    float2 lsp =
        *reinterpret_cast<const float2*>((char*)lv + (wave * 64 + lane) * 8);
    lsB += lsp.x;
    lsA += lsp.y;
    WAITLGKM();

    const int b = bh >> 4, hh = bh & 15;
    attn_epi(Ctx, lp[wave], oB, lsB, b, hh, qtB * 64 + rg * 16, lane);
    attn_epi(Ctx, lp[wave + 4], oA, lsA, b, hh, qtA * 64 + rg * 16, lane);
  }
}

// ---------------- launch ----------------
extern "C" void kernel_launch(void* const* d_in, const int* in_sizes, int n_in,
                              void* d_out, int out_size, void* d_ws,
                              size_t ws_size, hipStream_t stream) {
  const float* x = (const float*)d_in[0];
  const float* Wq = (const float*)d_in[1];
  const float* bq = (const float*)d_in[2];
  const float* Wk = (const float*)d_in[3];
  const float* bk = (const float*)d_in[4];
  const float* Wv = (const float*)d_in[5];
  const float* bv = (const float*)d_in[6];
  const float* Wo = (const float*)d_in[7];
  const float* bo = (const float*)d_in[8];
  float* out = (float*)d_out;

  char* ws = (char*)d_ws;
  unsigned short* xb = (unsigned short*)(ws);                    // 8 MB
  unsigned short* wqb = (unsigned short*)(ws + (8u << 20));      // 2 MB
  unsigned short* wkb = (unsigned short*)(ws + (10u << 20));
  unsigned short* wvb = (unsigned short*)(ws + (12u << 20));
  unsigned short* wob = (unsigned short*)(ws + (14u << 20));
  unsigned short* Qb = (unsigned short*)(ws + (16u << 20));      // 8 MB
  unsigned short* Kb = (unsigned short*)(ws + (24u << 20));      // 8 MB
  unsigned short* Vtb = (unsigned short*)(ws + (32u << 20));     // 8 MB
  unsigned short* Ctx = (unsigned short*)(ws + (40u << 20));     // 8 MB

  k_cvt_all<<<8192, 256, 0, stream>>>(x, Wq, Wk, Wv, Wo, xb);

  k_gemm_qkv<<<512, 256, 0, stream>>>(xb, wqb, wkb, wvb, bq, bk, bv,
                                      Qb, Kb, Vtb);
  k_attn<<<512, 512, 0, stream>>>(Qb, Kb, Vtb, Ctx);
  k_gemm_out<<<512, 256, 0, stream>>>(Ctx, wob, bo, out);
}